// Round 4
// baseline (798.982 us; speedup 1.0000x reference)
//
#include <hip/hip_runtime.h>
#include <math.h>

#define B_  32
#define L_  1024
#define M_  (B_*L_)      // 32768 rows
#define DM  128
#define DI  256
#define DS  16
#define DC  4
#define DR  8
#define NL  2

__device__ __forceinline__ float silu_f(float x) { return x / (1.f + expf(-x)); }
__device__ __forceinline__ float softplus_f(float x) {
    return fmaxf(x, 0.f) + log1pf(expf(-fabsf(x)));
}

// ---------------------------------------------------------------- PE table (sin/cos hoisted)
__global__ __launch_bounds__(256) void pe_kernel(float* __restrict__ pe) {
    int idx = blockIdx.x * 256 + threadIdx.x;     // over 1024*64
    int t = idx >> 6, i = idx & 63;
    float div = expf(-0.07195578415606394f * (float)(2 * i));  // -ln(10000)/128
    float ang = (float)t * div;
    pe[t * 128 + 2 * i]     = sinf(ang);
    pe[t * 128 + 2 * i + 1] = cosf(ang);
}

// ---------------------------------------------------------------- embed
__global__ __launch_bounds__(256) void embed_kernel(
        const float* __restrict__ x_enc, const float* __restrict__ x_mark,
        const float* __restrict__ tokW, const float* __restrict__ tempW,
        const float* __restrict__ pe, float* __restrict__ out) {
    int idx = blockIdx.x * 256 + threadIdx.x;      // over M_*DM
    int d = idx & 127;
    int m = idx >> 7;
    int b = m >> 10, t = m & 1023;
    const float* xb = x_enc + (size_t)b * L_ * 7;
    float acc = pe[t * 128 + d];
    #pragma unroll
    for (int w = 0; w < 3; ++w) {
        int tt = t + w - 1;
        tt = (tt < 0) ? (L_ - 1) : (tt >= L_ ? 0 : tt);   // circular pad
        const float* xr = xb + tt * 7;
        #pragma unroll
        for (int f = 0; f < 7; ++f) acc += xr[f] * tokW[(d * 7 + f) * 3 + w];
    }
    const float* mr = x_mark + (size_t)m * 4;
    #pragma unroll
    for (int f = 0; f < 4; ++f) acc += mr[f] * tempW[d * 4 + f];
    out[idx] = acc;
}

// ---------------------------------------------------------------- layernorm
__global__ __launch_bounds__(256) void ln_kernel(
        const float* __restrict__ a, const float* __restrict__ b,
        const float* __restrict__ w, const float* __restrict__ bias,
        float* __restrict__ out_ln, float* __restrict__ out_res) {
    int wv = threadIdx.x >> 6, lane = threadIdx.x & 63;
    size_t m = (size_t)blockIdx.x * 4 + wv;
    size_t base = m * DM;
    float x0 = a[base + lane], x1 = a[base + lane + 64];
    if (b) { x0 += b[base + lane]; x1 += b[base + lane + 64]; }
    if (out_res) { out_res[base + lane] = x0; out_res[base + lane + 64] = x1; }
    float s = x0 + x1;
    #pragma unroll
    for (int o = 1; o < 64; o <<= 1) s += __shfl_xor(s, o, 64);
    float mu = s * (1.f / 128.f);
    float d0 = x0 - mu, d1 = x1 - mu;
    float v = d0 * d0 + d1 * d1;
    #pragma unroll
    for (int o = 1; o < 64; o <<= 1) v += __shfl_xor(v, o, 64);
    float inv = rsqrtf(v * (1.f / 128.f) + 1e-5f);
    out_ln[base + lane]      = d0 * inv * w[lane]      + bias[lane];
    out_ln[base + lane + 64] = d1 * inv * w[lane + 64] + bias[lane + 64];
}

// ---------------------------------------------------------------- in_proj GEMM, both halves transposed out
// n<256  -> xiT[(b*256+n)*1024 + t]
// n>=256 -> zsilT[(b*256+(n-256))*1024 + t] = silu(val)
__global__ __launch_bounds__(256) void gemm_inproj(
        const float* __restrict__ A, const float* __restrict__ W,
        float* __restrict__ xiT, float* __restrict__ zsilT) {
    __shared__ float As[16][128];
    __shared__ float Ws[16][128];
    int bm = blockIdx.y * 128, bn = blockIdx.x * 128;
    int tid = threadIdx.x, tx = tid & 15, ty = tid >> 4;
    float acc[8][8] = {};
    for (int k0 = 0; k0 < 128; k0 += 16) {
        #pragma unroll
        for (int i = 0; i < 2; ++i) {
            int idx = tid * 2 + i;            // 0..511
            int row = idx >> 2, c4 = (idx & 3) * 4;
            float4 a4 = *(const float4*)(A + (size_t)(bm + row) * 128 + k0 + c4);
            As[c4 + 0][row] = a4.x; As[c4 + 1][row] = a4.y;
            As[c4 + 2][row] = a4.z; As[c4 + 3][row] = a4.w;
            float4 w4 = *(const float4*)(W + (size_t)(bn + row) * 128 + k0 + c4);
            Ws[c4 + 0][row] = w4.x; Ws[c4 + 1][row] = w4.y;
            Ws[c4 + 2][row] = w4.z; Ws[c4 + 3][row] = w4.w;
        }
        __syncthreads();
        #pragma unroll
        for (int k = 0; k < 16; ++k) {
            float a[8], bb[8];
            *(float4*)&a[0]  = *(float4*)&As[k][ty * 8];
            *(float4*)&a[4]  = *(float4*)&As[k][ty * 8 + 4];
            *(float4*)&bb[0] = *(float4*)&Ws[k][tx * 8];
            *(float4*)&bb[4] = *(float4*)&Ws[k][tx * 8 + 4];
            #pragma unroll
            for (int i = 0; i < 8; ++i)
                #pragma unroll
                for (int j = 0; j < 8; ++j) acc[i][j] += a[i] * bb[j];
        }
        __syncthreads();
    }
    int b = bm >> 10, t0 = (bm & 1023) + ty * 8;
    if (bn < 256) {
        #pragma unroll
        for (int j = 0; j < 8; ++j) {
            int xd = bn + tx * 8 + j;
            float r[8];
            #pragma unroll
            for (int i = 0; i < 8; ++i) r[i] = acc[i][j];
            float* dst = xiT + ((size_t)(b * 256 + xd)) * 1024 + t0;
            *(float4*)dst       = *(float4*)&r[0];
            *(float4*)(dst + 4) = *(float4*)&r[4];
        }
    } else {
        #pragma unroll
        for (int j = 0; j < 8; ++j) {
            int zd = bn - 256 + tx * 8 + j;
            float r[8];
            #pragma unroll
            for (int i = 0; i < 8; ++i) r[i] = silu_f(acc[i][j]);
            float* dst = zsilT + ((size_t)(b * 256 + zd)) * 1024 + t0;
            *(float4*)dst       = *(float4*)&r[0];
            *(float4*)(dst + 4) = *(float4*)&r[4];
        }
    }
}

// ---------------------------------------------------------------- GEMM 128x128 (A transposed: AT[(b*K)+e][t])
__global__ __launch_bounds__(256) void gemm_tn_128(
        const float* __restrict__ AT, const float* __restrict__ W,
        float* __restrict__ C, int M, int N, int K) {
    __shared__ float As[16][128];
    __shared__ float Ws[16][128];
    int bm = blockIdx.y * 128, bn = blockIdx.x * 128;
    int b = bm >> 10, tloc = bm & 1023;
    int tid = threadIdx.x, tx = tid & 15, ty = tid >> 4;
    float acc[8][8] = {};
    for (int k0 = 0; k0 < K; k0 += 16) {
        #pragma unroll
        for (int i = 0; i < 2; ++i) {
            int idx = tid * 2 + i;            // 0..511
            int k = idx >> 5, m4 = (idx & 31) * 4;
            float4 a4 = *(const float4*)(AT + ((size_t)b * K + k0 + k) * 1024 + tloc + m4);
            *(float4*)&As[k][m4] = a4;
            int row = idx >> 2, c4 = (idx & 3) * 4;
            float4 w4 = *(const float4*)(W + (size_t)(bn + row) * K + k0 + c4);
            Ws[c4 + 0][row] = w4.x; Ws[c4 + 1][row] = w4.y;
            Ws[c4 + 2][row] = w4.z; Ws[c4 + 3][row] = w4.w;
        }
        __syncthreads();
        #pragma unroll
        for (int k = 0; k < 16; ++k) {
            float a[8], bb[8];
            *(float4*)&a[0]  = *(float4*)&As[k][ty * 8];
            *(float4*)&a[4]  = *(float4*)&As[k][ty * 8 + 4];
            *(float4*)&bb[0] = *(float4*)&Ws[k][tx * 8];
            *(float4*)&bb[4] = *(float4*)&Ws[k][tx * 8 + 4];
            #pragma unroll
            for (int i = 0; i < 8; ++i)
                #pragma unroll
                for (int j = 0; j < 8; ++j) acc[i][j] += a[i] * bb[j];
        }
        __syncthreads();
    }
    #pragma unroll
    for (int i = 0; i < 8; ++i) {
        size_t row = (size_t)(bm + ty * 8 + i) * N + bn + tx * 8;
        *(float4*)(C + row)     = *(float4*)&acc[i][0];
        *(float4*)(C + row + 4) = *(float4*)&acc[i][4];
    }
}

// ---------------------------------------------------------------- GEMM 64x64 (A transposed), N small w/ guard
__global__ __launch_bounds__(256) void gemm_tn_64(
        const float* __restrict__ AT, const float* __restrict__ W,
        float* __restrict__ C, int M, int N, int K) {
    __shared__ float As[16][68];
    __shared__ float Ws[16][68];
    int bm = blockIdx.y * 64, bn = blockIdx.x * 64;
    int b = bm >> 10, tloc = bm & 1023;
    int tid = threadIdx.x, tx = tid & 15, ty = tid >> 4;
    float acc[4][4] = {};
    for (int k0 = 0; k0 < K; k0 += 16) {
        {
            int k = tid >> 4, m4 = (tid & 15) * 4;
            float4 a4 = *(const float4*)(AT + ((size_t)b * K + k0 + k) * 1024 + tloc + m4);
            *(float4*)&As[k][m4] = a4;
        }
        #pragma unroll
        for (int i = 0; i < 4; ++i) {
            int r = i * 16 + ty;
            int n = bn + r;
            Ws[tx][r] = (n < N) ? W[(size_t)n * K + k0 + tx] : 0.f;
        }
        __syncthreads();
        #pragma unroll
        for (int k = 0; k < 16; ++k) {
            float a[4], bb[4];
            #pragma unroll
            for (int i = 0; i < 4; ++i) a[i] = As[k][ty * 4 + i];
            #pragma unroll
            for (int j = 0; j < 4; ++j) bb[j] = Ws[k][tx * 4 + j];
            #pragma unroll
            for (int i = 0; i < 4; ++i)
                #pragma unroll
                for (int j = 0; j < 4; ++j) acc[i][j] += a[i] * bb[j];
        }
        __syncthreads();
    }
    #pragma unroll
    for (int i = 0; i < 4; ++i) {
        int m = bm + ty * 4 + i;
        #pragma unroll
        for (int j = 0; j < 4; ++j) {
            int n = bn + tx * 4 + j;
            if (n < N) C[(size_t)m * N + n] = acc[i][j];
        }
    }
}

// ---------------------------------------------------------------- conv + silu (T layout, contiguous per wave)
// uT[(b*256+d)*1024+t] = silu(conv(xiT row)), causal 4-tap
__global__ __launch_bounds__(256) void conv_T_kernel(
        const float* __restrict__ xiT, const float* __restrict__ cw,
        const float* __restrict__ cb, float* __restrict__ uT) {
    int wv = threadIdx.x >> 6, lane = threadIdx.x & 63;
    int rid = blockIdx.x * 4 + wv;            // b*256 + d
    int d = rid & 255;
    const float* src = xiT + (size_t)rid * 1024;
    int t0 = lane * 16;
    float x[20];
    {
        float4 p = (lane > 0) ? *(const float4*)(src + t0 - 4)
                              : make_float4(0.f, 0.f, 0.f, 0.f);
        *(float4*)&x[0] = p;
        #pragma unroll
        for (int c = 0; c < 4; ++c)
            *(float4*)&x[4 + c * 4] = *(const float4*)(src + t0 + c * 4);
    }
    float4 w4 = ((const float4*)cw)[d];
    float bias = cb[d];
    float* dst = uT + (size_t)rid * 1024 + t0;
    #pragma unroll
    for (int c = 0; c < 4; ++c) {
        float r[4];
        #pragma unroll
        for (int i = 0; i < 4; ++i) {
            int k = c * 4 + i;
            float acc = bias + x[k + 1] * w4.x + x[k + 2] * w4.y
                             + x[k + 3] * w4.z + x[k + 4] * w4.w;
            r[i] = silu_f(acc);
        }
        *(float4*)(dst + c * 4) = make_float4(r[0], r[1], r[2], r[3]);
    }
}

// ---------------------------------------------------------------- dbc -> dtT (proj+softplus) + BT/CT (transpose), fused
__global__ __launch_bounds__(256) void dbc_split_kernel(
        const float* __restrict__ dbc, const float* __restrict__ dtW,
        const float* __restrict__ dtb, float* __restrict__ dtT,
        float* __restrict__ BT, float* __restrict__ CT) {
    int m0 = blockIdx.x * 64;
    int b = m0 >> 10, t0 = m0 & 1023;
    // part 1: dtT — each thread = one n
    {
        int n = threadIdx.x;
        float4 wa = ((const float4*)dtW)[n * 2];
        float4 wb = ((const float4*)dtW)[n * 2 + 1];
        float bias = dtb[n];
        float* dst = dtT + ((size_t)(b * 256 + n)) * 1024 + t0;
        for (int r4 = 0; r4 < 64; r4 += 4) {
            float o[4];
            #pragma unroll
            for (int i = 0; i < 4; ++i) {
                const float* row = dbc + (size_t)(m0 + r4 + i) * 40;
                float acc = bias + row[0] * wa.x + row[1] * wa.y + row[2] * wa.z + row[3] * wa.w
                                 + row[4] * wb.x + row[5] * wb.y + row[6] * wb.z + row[7] * wb.w;
                o[i] = softplus_f(acc);
            }
            *(float4*)(dst + r4) = make_float4(o[0], o[1], o[2], o[3]);
        }
    }
    // part 2: B/C transpose — tid = s*8+q; s 0..31 (B then C), q = 8-t-chunk
    {
        int s = threadIdx.x >> 3, q = threadIdx.x & 7;
        const float* src = dbc + (size_t)m0 * 40 + 8 + s;
        float* outp = ((s < 16) ? BT : CT) + ((size_t)(b * 16 + (s & 15))) * 1024 + t0 + q * 8;
        float v[8];
        #pragma unroll
        for (int i = 0; i < 8; ++i) v[i] = src[(size_t)(q * 8 + i) * 40];
        *(float4*)outp       = make_float4(v[0], v[1], v[2], v[3]);
        *(float4*)(outp + 4) = make_float4(v[4], v[5], v[6], v[7]);
    }
}

// ---------------------------------------------------------------- scan v4: paired-state interleaved KS
// 512 thr = 8 waves = 8 d of one b. Lane owns 16 t. Per s-pair: 2 independent
// local passes + 2 interleaved Kogge-Stone chains (4 shfls in flight/stage).
__global__ __launch_bounds__(512) void scan4_kernel(
        const float* __restrict__ dtT, const float* __restrict__ uT,
        const float* __restrict__ BT, const float* __restrict__ CT,
        const float* __restrict__ A_log, const float* __restrict__ zsilT,
        const float* __restrict__ Dp, float* __restrict__ yT) {
    __shared__ float4 sB[2][4][65], sC[2][4][65];   // [65] pad: staging-write conflicts
    int wv = threadIdx.x >> 6, lane = threadIdx.x & 63;
    int b = blockIdx.x >> 5;
    int d = (blockIdx.x & 31) * 8 + wv;
    size_t base = ((size_t)(b * 256 + d)) * 1024 + lane * 16;

    float dt[16], du[16], y[16], pcA[16], pcB[16];
    {
        const float4* p = (const float4*)(dtT + base);
        const float4* q = (const float4*)(uT + base);
        #pragma unroll
        for (int c = 0; c < 4; ++c) {
            float4 dv = p[c], uv = q[c];
            dt[c * 4 + 0] = dv.x; dt[c * 4 + 1] = dv.y; dt[c * 4 + 2] = dv.z; dt[c * 4 + 3] = dv.w;
            du[c * 4 + 0] = dv.x * uv.x; du[c * 4 + 1] = dv.y * uv.y;
            du[c * 4 + 2] = dv.z * uv.z; du[c * 4 + 3] = dv.w * uv.w;
        }
        #pragma unroll
        for (int i = 0; i < 16; ++i) y[i] = 0.f;
    }
    const float4* BT4 = (const float4*)BT + (size_t)b * 16 * 256;
    const float4* CT4 = (const float4*)CT + (size_t)b * 16 * 256;
    const float* Arow = A_log + d * 16;

    for (int p = 0; p < 8; ++p) {
        int s0 = 2 * p, s1 = 2 * p + 1;
        __syncthreads();          // previous pair's LDS reads done
        {
            int w = threadIdx.x;
            if (w < 256) {
                sB[0][w & 3][w >> 2] = BT4[s0 * 256 + w];
                sB[1][w & 3][w >> 2] = BT4[s1 * 256 + w];
            } else {
                int w2 = w - 256;
                sC[0][w2 & 3][w2 >> 2] = CT4[s0 * 256 + w2];
                sC[1][w2 & 3][w2 >> 2] = CT4[s1 * 256 + w2];
            }
        }
        __syncthreads();
        float A2a = -expf(Arow[s0]) * 1.4426950408889634f;
        float A2b = -expf(Arow[s1]) * 1.4426950408889634f;
        float h0 = 0.f, P0 = 1.f, h1 = 0.f, P1 = 1.f;
        #pragma unroll
        for (int c = 0; c < 4; ++c) {
            float Bv0[4], Cv0[4], Bv1[4], Cv1[4];
            *(float4*)Bv0 = sB[0][c][lane]; *(float4*)Cv0 = sC[0][c][lane];
            *(float4*)Bv1 = sB[1][c][lane]; *(float4*)Cv1 = sC[1][c][lane];
            #pragma unroll
            for (int i = 0; i < 4; ++i) {
                int ii = c * 4 + i;
                float a0 = __builtin_amdgcn_exp2f(dt[ii] * A2a);
                float a1 = __builtin_amdgcn_exp2f(dt[ii] * A2b);
                h0 = a0 * h0 + du[ii] * Bv0[i];  P0 *= a0;
                h1 = a1 * h1 + du[ii] * Bv1[i];  P1 *= a1;
                y[ii] += h0 * Cv0[i] + h1 * Cv1[i];
                pcA[ii] = P0 * Cv0[i];
                pcB[ii] = P1 * Cv1[i];
            }
        }
        // two interleaved inclusive Kogge-Stone scans over (A=prod, E=end)
        float Aag0 = P0, E0 = h0, Aag1 = P1, E1 = h1;
        #pragma unroll
        for (int dlt = 1; dlt < 64; dlt <<= 1) {
            float Au0 = __shfl_up(Aag0, dlt, 64), Eu0 = __shfl_up(E0, dlt, 64);
            float Au1 = __shfl_up(Aag1, dlt, 64), Eu1 = __shfl_up(E1, dlt, 64);
            if (lane >= dlt) {
                E0 = Aag0 * Eu0 + E0;  Aag0 *= Au0;
                E1 = Aag1 * Eu1 + E1;  Aag1 *= Au1;
            }
        }
        float car0 = __shfl_up(E0, 1, 64), car1 = __shfl_up(E1, 1, 64);
        if (lane == 0) { car0 = 0.f; car1 = 0.f; }
        #pragma unroll
        for (int i = 0; i < 16; ++i) y[i] += car0 * pcA[i] + car1 * pcB[i];
    }

    // epilogue: u = du/dt (guarded); gate with u*D and pre-silu'd z
    float Dv = Dp[d];
    const float4* qz = (const float4*)(zsilT + base);
    float* dst = yT + base;
    #pragma unroll
    for (int c = 0; c < 4; ++c) {
        float4 zv = qz[c];
        float za[4] = {zv.x, zv.y, zv.z, zv.w};
        float r[4];
        #pragma unroll
        for (int i = 0; i < 4; ++i) {
            int ii = c * 4 + i;
            float u = (dt[ii] > 0.f) ? du[ii] * __builtin_amdgcn_rcpf(dt[ii]) : 0.f;
            r[i] = (y[ii] + u * Dv) * za[i];
        }
        *(float4*)(dst + c * 4) = make_float4(r[0], r[1], r[2], r[3]);
    }
}

// ---------------------------------------------------------------- final projection (C_OUT=7)
__global__ __launch_bounds__(256) void outproj_kernel(
        const float* __restrict__ x, const float* __restrict__ W,
        float* __restrict__ out) {
    int wv = threadIdx.x >> 6, lane = threadIdx.x & 63;
    size_t m = (size_t)blockIdx.x * 4 + wv;
    float x0 = x[m * 128 + lane], x1 = x[m * 128 + lane + 64];
    #pragma unroll
    for (int c = 0; c < 7; ++c) {
        float p = x0 * W[c * 128 + lane] + x1 * W[c * 128 + lane + 64];
        #pragma unroll
        for (int o = 1; o < 64; o <<= 1) p += __shfl_xor(p, o, 64);
        if (lane == 0) out[m * 7 + c] = p;
    }
}

// ================================================================ launch
extern "C" void kernel_launch(void* const* d_in, const int* in_sizes, int n_in,
                              void* d_out, int out_size, void* d_ws, size_t ws_size,
                              hipStream_t stream) {
    const float* x_enc  = (const float*)d_in[0];
    const float* x_mark = (const float*)d_in[1];
    const float* tokW   = (const float*)d_in[4];
    const float* tempW  = (const float*)d_in[5];
    const float* norm_w = (const float*)d_in[6];
    const float* norm_b = (const float*)d_in[7];
    const float* inW    = (const float*)d_in[8];
    const float* convW  = (const float*)d_in[9];
    const float* convB  = (const float*)d_in[10];
    const float* xpW    = (const float*)d_in[11];
    const float* dtW    = (const float*)d_in[12];
    const float* dtbp   = (const float*)d_in[13];
    const float* A_log  = (const float*)d_in[14];
    const float* Dp     = (const float*)d_in[15];
    const float* outW   = (const float*)d_in[16];
    const float* nfw    = (const float*)d_in[17];
    const float* nfb    = (const float*)d_in[18];
    const float* finW   = (const float*)d_in[19];
    float* out = (float*)d_out;

    float* ws = (float*)d_ws;
    size_t o = 0;
    float* hidden   = ws + o; o += (size_t)M_ * DM;
    float* residual = ws + o; o += (size_t)M_ * DM;
    float* xln      = ws + o; o += (size_t)M_ * DM;    // also hosts BT/CT after in_proj
    float* xiT      = ws + o; o += (size_t)M_ * DI;
    float* zsilT    = ws + o; o += (size_t)M_ * DI;
    float* uT       = ws + o; o += (size_t)M_ * DI;
    float* dbc      = ws + o; o += (size_t)M_ * 40;    // also hosts pe before layer loop
    float* dtT      = ws + o; o += (size_t)M_ * DI;
    float* yT       = ws + o; o += (size_t)M_ * DI;
    float* BT = xln;                                   // alias: xln dead after in_proj
    float* CT = xln + (size_t)B_ * DS * L_;
    float* pe = dbc;                                   // alias: pe dead before dbc written

    dim3 blk(256);
    pe_kernel<<<1024 * 64 / 256, blk, 0, stream>>>(pe);
    embed_kernel<<<M_ * DM / 256, blk, 0, stream>>>(x_enc, x_mark, tokW, tempW, pe, hidden);

    for (int l = 0; l < NL; ++l) {
        ln_kernel<<<M_ / 4, blk, 0, stream>>>(hidden, l ? residual : nullptr,
                                              norm_w + l * DM, norm_b + l * DM,
                                              xln, residual);
        // in_proj: xiT (cols<256, transposed) + silu(z) transposed (cols>=256)
        gemm_inproj<<<dim3(4, M_ / 128), blk, 0, stream>>>(
            xln, inW + (size_t)l * 512 * DM, xiT, zsilT);
        // uT = silu(causal depthwise conv(xiT)) — contiguous per-wave rows
        conv_T_kernel<<<B_ * DI / 4, blk, 0, stream>>>(xiT, convW + l * DI * DC,
                                                       convB + l * DI, uT);
        // dbc = u @ xp_W^T    (M x 40, K=256), A transposed
        gemm_tn_64<<<dim3(1, M_ / 64), blk, 0, stream>>>(
            uT, xpW + (size_t)l * 40 * DI, dbc, M_, 40, DI);
        // dtT = softplus(dbc[:,:8] @ dtW^T + dtb)^T ; BT/CT = transposes of dbc cols
        dbc_split_kernel<<<M_ / 64, blk, 0, stream>>>(dbc, dtW + l * DI * DR,
                                                      dtbp + l * DI, dtT, BT, CT);
        // scan + gate -> yT
        scan4_kernel<<<B_ * 32, dim3(512), 0, stream>>>(dtT, uT, BT, CT,
                                                        A_log + l * DI * DS, zsilT,
                                                        Dp + l * DI, yT);
        // hidden = y @ out_W^T  (M x 128, K=256), A transposed
        gemm_tn_128<<<dim3(1, M_ / 128), blk, 0, stream>>>(
            yT, outW + (size_t)l * DM * DI, hidden, M_, DM, DI);
    }

    ln_kernel<<<M_ / 4, blk, 0, stream>>>(hidden, residual, nfw, nfb, xln, nullptr);
    outproj_kernel<<<M_ / 4, blk, 0, stream>>>(xln, finW, out);
}

// Round 5
// 696.518 us; speedup vs baseline: 1.1471x; 1.1471x over previous
//
#include <hip/hip_runtime.h>
#include <math.h>

#define B_  32
#define L_  1024
#define M_  (B_*L_)      // 32768 rows
#define DM  128
#define DI  256
#define DS  16
#define DC  4
#define DR  8
#define NL  2

__device__ __forceinline__ float silu_f(float x) { return x / (1.f + expf(-x)); }
__device__ __forceinline__ float softplus_f(float x) {
    return fmaxf(x, 0.f) + log1pf(expf(-fabsf(x)));
}

// ---------------------------------------------------------------- PE table (sin/cos hoisted)
__global__ __launch_bounds__(256) void pe_kernel(float* __restrict__ pe) {
    int idx = blockIdx.x * 256 + threadIdx.x;     // over 1024*64
    int t = idx >> 6, i = idx & 63;
    float div = expf(-0.07195578415606394f * (float)(2 * i));  // -ln(10000)/128
    float ang = (float)t * div;
    pe[t * 128 + 2 * i]     = sinf(ang);
    pe[t * 128 + 2 * i + 1] = cosf(ang);
}

// ---------------------------------------------------------------- embed
__global__ __launch_bounds__(256) void embed_kernel(
        const float* __restrict__ x_enc, const float* __restrict__ x_mark,
        const float* __restrict__ tokW, const float* __restrict__ tempW,
        const float* __restrict__ pe, float* __restrict__ out) {
    int idx = blockIdx.x * 256 + threadIdx.x;      // over M_*DM
    int d = idx & 127;
    int m = idx >> 7;
    int b = m >> 10, t = m & 1023;
    const float* xb = x_enc + (size_t)b * L_ * 7;
    float acc = pe[t * 128 + d];
    #pragma unroll
    for (int w = 0; w < 3; ++w) {
        int tt = t + w - 1;
        tt = (tt < 0) ? (L_ - 1) : (tt >= L_ ? 0 : tt);   // circular pad
        const float* xr = xb + tt * 7;
        #pragma unroll
        for (int f = 0; f < 7; ++f) acc += xr[f] * tokW[(d * 7 + f) * 3 + w];
    }
    const float* mr = x_mark + (size_t)m * 4;
    #pragma unroll
    for (int f = 0; f < 4; ++f) acc += mr[f] * tempW[d * 4 + f];
    out[idx] = acc;
}

// ---------------------------------------------------------------- layernorm
__global__ __launch_bounds__(256) void ln_kernel(
        const float* __restrict__ a, const float* __restrict__ b,
        const float* __restrict__ w, const float* __restrict__ bias,
        float* __restrict__ out_ln, float* __restrict__ out_res) {
    int wv = threadIdx.x >> 6, lane = threadIdx.x & 63;
    size_t m = (size_t)blockIdx.x * 4 + wv;
    size_t base = m * DM;
    float x0 = a[base + lane], x1 = a[base + lane + 64];
    if (b) { x0 += b[base + lane]; x1 += b[base + lane + 64]; }
    if (out_res) { out_res[base + lane] = x0; out_res[base + lane + 64] = x1; }
    float s = x0 + x1;
    #pragma unroll
    for (int o = 1; o < 64; o <<= 1) s += __shfl_xor(s, o, 64);
    float mu = s * (1.f / 128.f);
    float d0 = x0 - mu, d1 = x1 - mu;
    float v = d0 * d0 + d1 * d1;
    #pragma unroll
    for (int o = 1; o < 64; o <<= 1) v += __shfl_xor(v, o, 64);
    float inv = rsqrtf(v * (1.f / 128.f) + 1e-5f);
    out_ln[base + lane]      = d0 * inv * w[lane]      + bias[lane];
    out_ln[base + lane + 64] = d1 * inv * w[lane + 64] + bias[lane + 64];
}

// ---------------------------------------------------------------- in_proj GEMM (BK=32), both halves transposed out
// n<256  -> xiT[(b*256+n)*1024 + t]
// n>=256 -> zsilT[(b*256+(n-256))*1024 + t] = silu(val)
__global__ __launch_bounds__(256) void gemm_inproj(
        const float* __restrict__ A, const float* __restrict__ W,
        float* __restrict__ xiT, float* __restrict__ zsilT) {
    __shared__ float As[32][128];
    __shared__ float Ws[32][128];
    int bm = blockIdx.y * 128, bn = blockIdx.x * 128;
    int tid = threadIdx.x, tx = tid & 15, ty = tid >> 4;
    float acc[8][8] = {};
    for (int k0 = 0; k0 < 128; k0 += 32) {
        #pragma unroll
        for (int i = 0; i < 4; ++i) {
            int idx = i * 256 + tid;          // 0..1023
            int row = idx >> 3, c4 = (idx & 7) * 4;
            float4 a4 = *(const float4*)(A + (size_t)(bm + row) * 128 + k0 + c4);
            As[c4 + 0][row] = a4.x; As[c4 + 1][row] = a4.y;
            As[c4 + 2][row] = a4.z; As[c4 + 3][row] = a4.w;
            float4 w4 = *(const float4*)(W + (size_t)(bn + row) * 128 + k0 + c4);
            Ws[c4 + 0][row] = w4.x; Ws[c4 + 1][row] = w4.y;
            Ws[c4 + 2][row] = w4.z; Ws[c4 + 3][row] = w4.w;
        }
        __syncthreads();
        #pragma unroll
        for (int k = 0; k < 32; ++k) {
            float a[8], bb[8];
            *(float4*)&a[0]  = *(float4*)&As[k][ty * 8];
            *(float4*)&a[4]  = *(float4*)&As[k][ty * 8 + 4];
            *(float4*)&bb[0] = *(float4*)&Ws[k][tx * 8];
            *(float4*)&bb[4] = *(float4*)&Ws[k][tx * 8 + 4];
            #pragma unroll
            for (int i = 0; i < 8; ++i)
                #pragma unroll
                for (int j = 0; j < 8; ++j) acc[i][j] += a[i] * bb[j];
        }
        __syncthreads();
    }
    int b = bm >> 10, t0 = (bm & 1023) + ty * 8;
    if (bn < 256) {
        #pragma unroll
        for (int j = 0; j < 8; ++j) {
            int xd = bn + tx * 8 + j;
            float r[8];
            #pragma unroll
            for (int i = 0; i < 8; ++i) r[i] = acc[i][j];
            float* dst = xiT + ((size_t)(b * 256 + xd)) * 1024 + t0;
            *(float4*)dst       = *(float4*)&r[0];
            *(float4*)(dst + 4) = *(float4*)&r[4];
        }
    } else {
        #pragma unroll
        for (int j = 0; j < 8; ++j) {
            int zd = bn - 256 + tx * 8 + j;
            float r[8];
            #pragma unroll
            for (int i = 0; i < 8; ++i) r[i] = silu_f(acc[i][j]);
            float* dst = zsilT + ((size_t)(b * 256 + zd)) * 1024 + t0;
            *(float4*)dst       = *(float4*)&r[0];
            *(float4*)(dst + 4) = *(float4*)&r[4];
        }
    }
}

// ---------------------------------------------------------------- GEMM 128x128 (BK=32, A transposed: AT[(b*K)+e][t])
__global__ __launch_bounds__(256) void gemm_tn_128(
        const float* __restrict__ AT, const float* __restrict__ W,
        float* __restrict__ C, int M, int N, int K) {
    __shared__ float As[32][128];
    __shared__ float Ws[32][128];
    int bm = blockIdx.y * 128, bn = blockIdx.x * 128;
    int b = bm >> 10, tloc = bm & 1023;
    int tid = threadIdx.x, tx = tid & 15, ty = tid >> 4;
    float acc[8][8] = {};
    for (int k0 = 0; k0 < K; k0 += 32) {
        #pragma unroll
        for (int i = 0; i < 4; ++i) {
            int idx = i * 256 + tid;          // 0..1023
            int k = idx >> 5, m4 = (idx & 31) * 4;
            float4 a4 = *(const float4*)(AT + ((size_t)b * K + k0 + k) * 1024 + tloc + m4);
            *(float4*)&As[k][m4] = a4;
            int row = idx >> 3, c4 = (idx & 7) * 4;
            float4 w4 = *(const float4*)(W + (size_t)(bn + row) * K + k0 + c4);
            Ws[c4 + 0][row] = w4.x; Ws[c4 + 1][row] = w4.y;
            Ws[c4 + 2][row] = w4.z; Ws[c4 + 3][row] = w4.w;
        }
        __syncthreads();
        #pragma unroll
        for (int k = 0; k < 32; ++k) {
            float a[8], bb[8];
            *(float4*)&a[0]  = *(float4*)&As[k][ty * 8];
            *(float4*)&a[4]  = *(float4*)&As[k][ty * 8 + 4];
            *(float4*)&bb[0] = *(float4*)&Ws[k][tx * 8];
            *(float4*)&bb[4] = *(float4*)&Ws[k][tx * 8 + 4];
            #pragma unroll
            for (int i = 0; i < 8; ++i)
                #pragma unroll
                for (int j = 0; j < 8; ++j) acc[i][j] += a[i] * bb[j];
        }
        __syncthreads();
    }
    #pragma unroll
    for (int i = 0; i < 8; ++i) {
        size_t row = (size_t)(bm + ty * 8 + i) * N + bn + tx * 8;
        *(float4*)(C + row)     = *(float4*)&acc[i][0];
        *(float4*)(C + row + 4) = *(float4*)&acc[i][4];
    }
}

// ---------------------------------------------------------------- GEMM 64x64 (A transposed), N small w/ guard
__global__ __launch_bounds__(256) void gemm_tn_64(
        const float* __restrict__ AT, const float* __restrict__ W,
        float* __restrict__ C, int M, int N, int K) {
    __shared__ float As[16][68];
    __shared__ float Ws[16][68];
    int bm = blockIdx.y * 64, bn = blockIdx.x * 64;
    int b = bm >> 10, tloc = bm & 1023;
    int tid = threadIdx.x, tx = tid & 15, ty = tid >> 4;
    float acc[4][4] = {};
    for (int k0 = 0; k0 < K; k0 += 16) {
        {
            int k = tid >> 4, m4 = (tid & 15) * 4;
            float4 a4 = *(const float4*)(AT + ((size_t)b * K + k0 + k) * 1024 + tloc + m4);
            *(float4*)&As[k][m4] = a4;
        }
        #pragma unroll
        for (int i = 0; i < 4; ++i) {
            int r = i * 16 + ty;
            int n = bn + r;
            Ws[tx][r] = (n < N) ? W[(size_t)n * K + k0 + tx] : 0.f;
        }
        __syncthreads();
        #pragma unroll
        for (int k = 0; k < 16; ++k) {
            float a[4], bb[4];
            #pragma unroll
            for (int i = 0; i < 4; ++i) a[i] = As[k][ty * 4 + i];
            #pragma unroll
            for (int j = 0; j < 4; ++j) bb[j] = Ws[k][tx * 4 + j];
            #pragma unroll
            for (int i = 0; i < 4; ++i)
                #pragma unroll
                for (int j = 0; j < 4; ++j) acc[i][j] += a[i] * bb[j];
        }
        __syncthreads();
    }
    #pragma unroll
    for (int i = 0; i < 4; ++i) {
        int m = bm + ty * 4 + i;
        #pragma unroll
        for (int j = 0; j < 4; ++j) {
            int n = bn + tx * 4 + j;
            if (n < N) C[(size_t)m * N + n] = acc[i][j];
        }
    }
}

// ---------------------------------------------------------------- conv + silu (T layout, contiguous per wave)
__global__ __launch_bounds__(256) void conv_T_kernel(
        const float* __restrict__ xiT, const float* __restrict__ cw,
        const float* __restrict__ cb, float* __restrict__ uT) {
    int wv = threadIdx.x >> 6, lane = threadIdx.x & 63;
    int rid = blockIdx.x * 4 + wv;            // b*256 + d
    int d = rid & 255;
    const float* src = xiT + (size_t)rid * 1024;
    int t0 = lane * 16;
    float x[20];
    {
        float4 p = (lane > 0) ? *(const float4*)(src + t0 - 4)
                              : make_float4(0.f, 0.f, 0.f, 0.f);
        *(float4*)&x[0] = p;
        #pragma unroll
        for (int c = 0; c < 4; ++c)
            *(float4*)&x[4 + c * 4] = *(const float4*)(src + t0 + c * 4);
    }
    float4 w4 = ((const float4*)cw)[d];
    float bias = cb[d];
    float* dst = uT + (size_t)rid * 1024 + t0;
    #pragma unroll
    for (int c = 0; c < 4; ++c) {
        float r[4];
        #pragma unroll
        for (int i = 0; i < 4; ++i) {
            int k = c * 4 + i;
            float acc = bias + x[k + 1] * w4.x + x[k + 2] * w4.y
                             + x[k + 3] * w4.z + x[k + 4] * w4.w;
            r[i] = silu_f(acc);
        }
        *(float4*)(dst + c * 4) = make_float4(r[0], r[1], r[2], r[3]);
    }
}

// ---------------------------------------------------------------- dbc -> dtT (proj+softplus) + BT/CT (transpose), fused
__global__ __launch_bounds__(256) void dbc_split_kernel(
        const float* __restrict__ dbc, const float* __restrict__ dtW,
        const float* __restrict__ dtb, float* __restrict__ dtT,
        float* __restrict__ BT, float* __restrict__ CT) {
    int m0 = blockIdx.x * 64;
    int b = m0 >> 10, t0 = m0 & 1023;
    // part 1: dtT — each thread = one n
    {
        int n = threadIdx.x;
        float4 wa = ((const float4*)dtW)[n * 2];
        float4 wb = ((const float4*)dtW)[n * 2 + 1];
        float bias = dtb[n];
        float* dst = dtT + ((size_t)(b * 256 + n)) * 1024 + t0;
        for (int r4 = 0; r4 < 64; r4 += 4) {
            float o[4];
            #pragma unroll
            for (int i = 0; i < 4; ++i) {
                const float* row = dbc + (size_t)(m0 + r4 + i) * 40;
                float acc = bias + row[0] * wa.x + row[1] * wa.y + row[2] * wa.z + row[3] * wa.w
                                 + row[4] * wb.x + row[5] * wb.y + row[6] * wb.z + row[7] * wb.w;
                o[i] = softplus_f(acc);
            }
            *(float4*)(dst + r4) = make_float4(o[0], o[1], o[2], o[3]);
        }
    }
    // part 2: B/C transpose — tid = s*8+q; s 0..31 (B then C), q = 8-t-chunk
    {
        int s = threadIdx.x >> 3, q = threadIdx.x & 7;
        const float* src = dbc + (size_t)m0 * 40 + 8 + s;
        float* outp = ((s < 16) ? BT : CT) + ((size_t)(b * 16 + (s & 15))) * 1024 + t0 + q * 8;
        float v[8];
        #pragma unroll
        for (int i = 0; i < 8; ++i) v[i] = src[(size_t)(q * 8 + i) * 40];
        *(float4*)outp       = make_float4(v[0], v[1], v[2], v[3]);
        *(float4*)(outp + 4) = make_float4(v[4], v[5], v[6], v[7]);
    }
}

// ---------------------------------------------------------------- scan v5: barrier-free, LDS-free
// one wave per (b,d); lane owns 16 t; per s-pair: direct coalesced global
// loads of B/C into regs, 2 interleaved Kogge-Stone chains. No __syncthreads.
__global__ __launch_bounds__(256) void scan5_kernel(
        const float* __restrict__ dtT, const float* __restrict__ uT,
        const float* __restrict__ BT, const float* __restrict__ CT,
        const float* __restrict__ A_log, const float* __restrict__ zsilT,
        const float* __restrict__ Dp, float* __restrict__ yT) {
    int wv = threadIdx.x >> 6, lane = threadIdx.x & 63;
    int wid = blockIdx.x * 4 + wv;            // b*256 + d
    int b = wid >> 8, d = wid & 255;
    size_t base = (size_t)wid * 1024 + lane * 16;

    float dt[16], du[16], y[16], pcA[16], pcB[16];
    {
        const float4* p = (const float4*)(dtT + base);
        const float4* q = (const float4*)(uT + base);
        #pragma unroll
        for (int c = 0; c < 4; ++c) {
            float4 dv = p[c], uv = q[c];
            dt[c * 4 + 0] = dv.x; dt[c * 4 + 1] = dv.y; dt[c * 4 + 2] = dv.z; dt[c * 4 + 3] = dv.w;
            du[c * 4 + 0] = dv.x * uv.x; du[c * 4 + 1] = dv.y * uv.y;
            du[c * 4 + 2] = dv.z * uv.z; du[c * 4 + 3] = dv.w * uv.w;
        }
        #pragma unroll
        for (int i = 0; i < 16; ++i) y[i] = 0.f;
    }
    const float* Bb = BT + (size_t)b * 16 * 1024 + lane * 16;
    const float* Cb = CT + (size_t)b * 16 * 1024 + lane * 16;
    const float* Arow = A_log + d * 16;

    for (int p = 0; p < 8; ++p) {
        int s0 = 2 * p, s1 = 2 * p + 1;
        float4 B0[4], B1[4], C0[4], C1[4];
        #pragma unroll
        for (int c = 0; c < 4; ++c) {
            B0[c] = *(const float4*)(Bb + (size_t)s0 * 1024 + c * 4);
            B1[c] = *(const float4*)(Bb + (size_t)s1 * 1024 + c * 4);
            C0[c] = *(const float4*)(Cb + (size_t)s0 * 1024 + c * 4);
            C1[c] = *(const float4*)(Cb + (size_t)s1 * 1024 + c * 4);
        }
        float A2a = -expf(Arow[s0]) * 1.4426950408889634f;
        float A2b = -expf(Arow[s1]) * 1.4426950408889634f;
        float h0 = 0.f, P0 = 1.f, h1 = 0.f, P1 = 1.f;
        #pragma unroll
        for (int c = 0; c < 4; ++c) {
            float Bv0[4] = {B0[c].x, B0[c].y, B0[c].z, B0[c].w};
            float Cv0[4] = {C0[c].x, C0[c].y, C0[c].z, C0[c].w};
            float Bv1[4] = {B1[c].x, B1[c].y, B1[c].z, B1[c].w};
            float Cv1[4] = {C1[c].x, C1[c].y, C1[c].z, C1[c].w};
            #pragma unroll
            for (int i = 0; i < 4; ++i) {
                int ii = c * 4 + i;
                float a0 = __builtin_amdgcn_exp2f(dt[ii] * A2a);
                float a1 = __builtin_amdgcn_exp2f(dt[ii] * A2b);
                h0 = a0 * h0 + du[ii] * Bv0[i];  P0 *= a0;
                h1 = a1 * h1 + du[ii] * Bv1[i];  P1 *= a1;
                y[ii] += h0 * Cv0[i] + h1 * Cv1[i];
                pcA[ii] = P0 * Cv0[i];
                pcB[ii] = P1 * Cv1[i];
            }
        }
        // two interleaved inclusive Kogge-Stone scans over (A=prod, E=end)
        float Aag0 = P0, E0 = h0, Aag1 = P1, E1 = h1;
        #pragma unroll
        for (int dlt = 1; dlt < 64; dlt <<= 1) {
            float Au0 = __shfl_up(Aag0, dlt, 64), Eu0 = __shfl_up(E0, dlt, 64);
            float Au1 = __shfl_up(Aag1, dlt, 64), Eu1 = __shfl_up(E1, dlt, 64);
            if (lane >= dlt) {
                E0 = Aag0 * Eu0 + E0;  Aag0 *= Au0;
                E1 = Aag1 * Eu1 + E1;  Aag1 *= Au1;
            }
        }
        float car0 = __shfl_up(E0, 1, 64), car1 = __shfl_up(E1, 1, 64);
        if (lane == 0) { car0 = 0.f; car1 = 0.f; }
        #pragma unroll
        for (int i = 0; i < 16; ++i) y[i] += car0 * pcA[i] + car1 * pcB[i];
    }

    // epilogue: u = du/dt (guarded); gate with u*D and pre-silu'd z
    float Dv = Dp[d];
    const float4* qz = (const float4*)(zsilT + base);
    float* dst = yT + base;
    #pragma unroll
    for (int c = 0; c < 4; ++c) {
        float4 zv = qz[c];
        float za[4] = {zv.x, zv.y, zv.z, zv.w};
        float r[4];
        #pragma unroll
        for (int i = 0; i < 4; ++i) {
            int ii = c * 4 + i;
            float u = (dt[ii] > 0.f) ? du[ii] * __builtin_amdgcn_rcpf(dt[ii]) : 0.f;
            r[i] = (y[ii] + u * Dv) * za[i];
        }
        *(float4*)(dst + c * 4) = make_float4(r[0], r[1], r[2], r[3]);
    }
}

// ---------------------------------------------------------------- final projection (C_OUT=7)
__global__ __launch_bounds__(256) void outproj_kernel(
        const float* __restrict__ x, const float* __restrict__ W,
        float* __restrict__ out) {
    int wv = threadIdx.x >> 6, lane = threadIdx.x & 63;
    size_t m = (size_t)blockIdx.x * 4 + wv;
    float x0 = x[m * 128 + lane], x1 = x[m * 128 + lane + 64];
    #pragma unroll
    for (int c = 0; c < 7; ++c) {
        float p = x0 * W[c * 128 + lane] + x1 * W[c * 128 + lane + 64];
        #pragma unroll
        for (int o = 1; o < 64; o <<= 1) p += __shfl_xor(p, o, 64);
        if (lane == 0) out[m * 7 + c] = p;
    }
}

// ================================================================ launch
extern "C" void kernel_launch(void* const* d_in, const int* in_sizes, int n_in,
                              void* d_out, int out_size, void* d_ws, size_t ws_size,
                              hipStream_t stream) {
    const float* x_enc  = (const float*)d_in[0];
    const float* x_mark = (const float*)d_in[1];
    const float* tokW   = (const float*)d_in[4];
    const float* tempW  = (const float*)d_in[5];
    const float* norm_w = (const float*)d_in[6];
    const float* norm_b = (const float*)d_in[7];
    const float* inW    = (const float*)d_in[8];
    const float* convW  = (const float*)d_in[9];
    const float* convB  = (const float*)d_in[10];
    const float* xpW    = (const float*)d_in[11];
    const float* dtW    = (const float*)d_in[12];
    const float* dtbp   = (const float*)d_in[13];
    const float* A_log  = (const float*)d_in[14];
    const float* Dp     = (const float*)d_in[15];
    const float* outW   = (const float*)d_in[16];
    const float* nfw    = (const float*)d_in[17];
    const float* nfb    = (const float*)d_in[18];
    const float* finW   = (const float*)d_in[19];
    float* out = (float*)d_out;

    float* ws = (float*)d_ws;
    size_t o = 0;
    float* hidden   = ws + o; o += (size_t)M_ * DM;
    float* residual = ws + o; o += (size_t)M_ * DM;
    float* xln      = ws + o; o += (size_t)M_ * DM;    // also hosts BT/CT after in_proj
    float* xiT      = ws + o; o += (size_t)M_ * DI;
    float* zsilT    = ws + o; o += (size_t)M_ * DI;
    float* uT       = ws + o; o += (size_t)M_ * DI;
    float* dbc      = ws + o; o += (size_t)M_ * 40;    // also hosts pe before layer loop
    float* dtT      = ws + o; o += (size_t)M_ * DI;
    float* yT       = ws + o; o += (size_t)M_ * DI;
    float* BT = xln;                                   // alias: xln dead after in_proj
    float* CT = xln + (size_t)B_ * DS * L_;
    float* pe = dbc;                                   // alias: pe dead before dbc written

    dim3 blk(256);
    pe_kernel<<<1024 * 64 / 256, blk, 0, stream>>>(pe);
    embed_kernel<<<M_ * DM / 256, blk, 0, stream>>>(x_enc, x_mark, tokW, tempW, pe, hidden);

    for (int l = 0; l < NL; ++l) {
        ln_kernel<<<M_ / 4, blk, 0, stream>>>(hidden, l ? residual : nullptr,
                                              norm_w + l * DM, norm_b + l * DM,
                                              xln, residual);
        // in_proj: xiT (cols<256, transposed) + silu(z) transposed (cols>=256)
        gemm_inproj<<<dim3(4, M_ / 128), blk, 0, stream>>>(
            xln, inW + (size_t)l * 512 * DM, xiT, zsilT);
        // uT = silu(causal depthwise conv(xiT)) — contiguous per-wave rows
        conv_T_kernel<<<B_ * DI / 4, blk, 0, stream>>>(xiT, convW + l * DI * DC,
                                                       convB + l * DI, uT);
        // dbc = u @ xp_W^T    (M x 40, K=256), A transposed
        gemm_tn_64<<<dim3(1, M_ / 64), blk, 0, stream>>>(
            uT, xpW + (size_t)l * 40 * DI, dbc, M_, 40, DI);
        // dtT = softplus(dbc[:,:8] @ dtW^T + dtb)^T ; BT/CT = transposes of dbc cols
        dbc_split_kernel<<<M_ / 64, blk, 0, stream>>>(dbc, dtW + l * DI * DR,
                                                      dtbp + l * DI, dtT, BT, CT);
        // scan + gate -> yT (barrier-free)
        scan5_kernel<<<B_ * DI / 4, blk, 0, stream>>>(dtT, uT, BT, CT,
                                                      A_log + l * DI * DS, zsilT,
                                                      Dp + l * DI, yT);
        // hidden = y @ out_W^T  (M x 128, K=256), A transposed
        gemm_tn_128<<<dim3(1, M_ / 128), blk, 0, stream>>>(
            yT, outW + (size_t)l * DM * DI, hidden, M_, DM, DI);
    }

    ln_kernel<<<M_ / 4, blk, 0, stream>>>(hidden, residual, nfw, nfb, xln, nullptr);
    outproj_kernel<<<M_ / 4, blk, 0, stream>>>(xln, finW, out);
}

// Round 7
// 629.396 us; speedup vs baseline: 1.2694x; 1.1066x over previous
//
#include <hip/hip_runtime.h>
#include <math.h>

#define B_  32
#define L_  1024
#define M_  (B_*L_)      // 32768 rows
#define DM  128
#define DI  256
#define DS  16
#define DC  4
#define DR  8
#define NL  2

typedef unsigned int  uint32;
typedef unsigned short ush;
typedef __attribute__((ext_vector_type(8))) short bf16x8;
typedef __attribute__((ext_vector_type(4))) float f32x4;

__device__ __forceinline__ float silu_f(float x) { return x / (1.f + expf(-x)); }
__device__ __forceinline__ float softplus_f(float x) {
    return fmaxf(x, 0.f) + log1pf(expf(-fabsf(x)));
}
// bf16 RNE round
__device__ __forceinline__ ush f2bf(float x) {
    union { float f; uint32 u; } v; v.f = x;
    uint32 lsb = (v.u >> 16) & 1u;
    v.u += 0x7fffu + lsb;
    return (ush)(v.u >> 16);
}
__device__ __forceinline__ void split2(float x, ush& h, ush& l) {
    h = f2bf(x);
    float fh = __uint_as_float(((uint32)h) << 16);
    l = f2bf(x - fh);
}
__device__ __forceinline__ uint32 pack_pair(float x) {
    ush h, l; split2(x, h, l);
    return (uint32)h | ((uint32)l << 16);
}
__device__ __forceinline__ float unpack_pair(uint32 v) {
    return __uint_as_float(v << 16) + __uint_as_float(v & 0xffff0000u);
}

// ---------------------------------------------------------------- weight split
__global__ __launch_bounds__(256) void cvt_pair_kernel(
        const float* __restrict__ src, ush* __restrict__ h, ush* __restrict__ l, int n) {
    int i = blockIdx.x * 256 + threadIdx.x;
    if (i < n) { ush hh, ll; split2(src[i], hh, ll); h[i] = hh; l[i] = ll; }
}

// ---------------------------------------------------------------- PE table
__global__ __launch_bounds__(256) void pe_kernel(float* __restrict__ pe) {
    int idx = blockIdx.x * 256 + threadIdx.x;     // over 1024*64
    int t = idx >> 6, i = idx & 63;
    float div = expf(-0.07195578415606394f * (float)(2 * i));  // -ln(10000)/128
    float ang = (float)t * div;
    pe[t * 128 + 2 * i]     = sinf(ang);
    pe[t * 128 + 2 * i + 1] = cosf(ang);
}

// ---------------------------------------------------------------- embed
__global__ __launch_bounds__(256) void embed_kernel(
        const float* __restrict__ x_enc, const float* __restrict__ x_mark,
        const float* __restrict__ tokW, const float* __restrict__ tempW,
        const float* __restrict__ pe, float* __restrict__ out) {
    int idx = blockIdx.x * 256 + threadIdx.x;      // over M_*DM
    int d = idx & 127;
    int m = idx >> 7;
    int b = m >> 10, t = m & 1023;
    const float* xb = x_enc + (size_t)b * L_ * 7;
    float acc = pe[t * 128 + d];
    #pragma unroll
    for (int w = 0; w < 3; ++w) {
        int tt = t + w - 1;
        tt = (tt < 0) ? (L_ - 1) : (tt >= L_ ? 0 : tt);   // circular pad
        const float* xr = xb + tt * 7;
        #pragma unroll
        for (int f = 0; f < 7; ++f) acc += xr[f] * tokW[(d * 7 + f) * 3 + w];
    }
    const float* mr = x_mark + (size_t)m * 4;
    #pragma unroll
    for (int f = 0; f < 4; ++f) acc += mr[f] * tempW[d * 4 + f];
    out[idx] = acc;
}

// ---------------------------------------------------------------- layernorm
// layer mode: outh/outl bf16 planes; final mode: out_f32
__global__ __launch_bounds__(256) void ln_kernel(
        const float* __restrict__ a, const float* __restrict__ b,
        const float* __restrict__ w, const float* __restrict__ bias,
        float* __restrict__ out_f32, ush* __restrict__ outh, ush* __restrict__ outl,
        float* __restrict__ out_res) {
    int wv = threadIdx.x >> 6, lane = threadIdx.x & 63;
    size_t m = (size_t)blockIdx.x * 4 + wv;
    size_t base = m * DM;
    float x0 = a[base + lane], x1 = a[base + lane + 64];
    if (b) { x0 += b[base + lane]; x1 += b[base + lane + 64]; }
    if (out_res) { out_res[base + lane] = x0; out_res[base + lane + 64] = x1; }
    float s = x0 + x1;
    #pragma unroll
    for (int o = 1; o < 64; o <<= 1) s += __shfl_xor(s, o, 64);
    float mu = s * (1.f / 128.f);
    float d0 = x0 - mu, d1 = x1 - mu;
    float v = d0 * d0 + d1 * d1;
    #pragma unroll
    for (int o = 1; o < 64; o <<= 1) v += __shfl_xor(v, o, 64);
    float inv = rsqrtf(v * (1.f / 128.f) + 1e-5f);
    float r0 = d0 * inv * w[lane]      + bias[lane];
    float r1 = d1 * inv * w[lane + 64] + bias[lane + 64];
    if (out_f32) {
        out_f32[base + lane] = r0; out_f32[base + lane + 64] = r1;
    } else {
        ush h, l;
        split2(r0, h, l); outh[base + lane] = h;      outl[base + lane] = l;
        split2(r1, h, l); outh[base + lane + 64] = h; outl[base + lane + 64] = l;
    }
}

// ---------------------------------------------------------------- in_proj MFMA (split-bf16, no LDS)
// A planes [M][128]; W planes [512][128]; out xiT / zsilT (transposed fp32)
__global__ __launch_bounds__(256) void gemm_inproj_mfma(
        const ush* __restrict__ Ah, const ush* __restrict__ Al,
        const ush* __restrict__ Wh, const ush* __restrict__ Wl,
        float* __restrict__ xiT, float* __restrict__ zsilT) {
    int bm = blockIdx.y * 128, bn = blockIdx.x * 128;
    int w = threadIdx.x >> 6, l = threadIdx.x & 63;
    int lm = l & 15, lk8 = (l >> 4) * 8;
    f32x4 acc[2][8];
    #pragma unroll
    for (int mi = 0; mi < 2; ++mi)
        #pragma unroll
        for (int ni = 0; ni < 8; ++ni) acc[mi][ni] = {0.f, 0.f, 0.f, 0.f};
    const ush* ah = Ah + (size_t)(bm + w * 32 + lm) * 128;
    const ush* al = Al + (size_t)(bm + w * 32 + lm) * 128;
    const ush* wh = Wh + (size_t)(bn + lm) * 128;
    const ush* wl = Wl + (size_t)(bn + lm) * 128;
    for (int k0 = 0; k0 < 128; k0 += 32) {
        bf16x8 aH[2], aL[2];
        #pragma unroll
        for (int mi = 0; mi < 2; ++mi) {
            aH[mi] = *(const bf16x8*)(ah + mi * 16 * 128 + k0 + lk8);
            aL[mi] = *(const bf16x8*)(al + mi * 16 * 128 + k0 + lk8);
        }
        #pragma unroll
        for (int ni = 0; ni < 8; ++ni) {
            bf16x8 wH = *(const bf16x8*)(wh + ni * 16 * 128 + k0 + lk8);
            bf16x8 wLo = *(const bf16x8*)(wl + ni * 16 * 128 + k0 + lk8);
            #pragma unroll
            for (int mi = 0; mi < 2; ++mi) {
                acc[mi][ni] = __builtin_amdgcn_mfma_f32_16x16x32_bf16(aL[mi], wH,  acc[mi][ni], 0, 0, 0);
                acc[mi][ni] = __builtin_amdgcn_mfma_f32_16x16x32_bf16(aH[mi], wLo, acc[mi][ni], 0, 0, 0);
                acc[mi][ni] = __builtin_amdgcn_mfma_f32_16x16x32_bf16(aH[mi], wH,  acc[mi][ni], 0, 0, 0);
            }
        }
    }
    int b = bm >> 10;
    int tl0 = (bm & 1023) + w * 32 + (l >> 4) * 4;
    #pragma unroll
    for (int ni = 0; ni < 8; ++ni) {
        int n = bn + ni * 16 + lm;
        #pragma unroll
        for (int mi = 0; mi < 2; ++mi) {
            int tl = tl0 + mi * 16;
            f32x4 v = acc[mi][ni];
            if (bn < 256) {
                *(f32x4*)(xiT + ((size_t)(b * 256 + n)) * 1024 + tl) = v;
            } else {
                f32x4 r;
                #pragma unroll
                for (int i = 0; i < 4; ++i) r[i] = silu_f(v[i]);
                *(f32x4*)(zsilT + ((size_t)(b * 256 + n - 256)) * 1024 + tl) = r;
            }
        }
    }
}

// ---------------------------------------------------------------- A-transposed MFMA GEMM (split-bf16)
// A32: packed (hi|lo<<16) [(b*KTOT+k)][1024]; W planes [N][KTOT]
// Cnm: [n][M] transposed out (float4 along m)  OR  Cmn: [m][Nvalid]
template<int NF, int KTOT>
__global__ __launch_bounds__(256) void gemm_at_mfma(
        const uint32* __restrict__ A32, const ush* __restrict__ Wh,
        const ush* __restrict__ Wl, int Nvalid,
        float* __restrict__ Cnm, float* __restrict__ Cmn) {
    __shared__ uint32 As[128][68];   // BK=64 interleaved hi|lo, stride 68 -> 16B aligned rows
    int bm = blockIdx.x * 128;
    int b = bm >> 10, tloc = bm & 1023;
    int tid = threadIdx.x;
    int w = tid >> 6, l = tid & 63;
    int lm = l & 15, lk8 = (l >> 4) * 8;
    f32x4 acc[2][NF];
    #pragma unroll
    for (int mi = 0; mi < 2; ++mi)
        #pragma unroll
        for (int ni = 0; ni < NF; ++ni) acc[mi][ni] = {0.f, 0.f, 0.f, 0.f};

    for (int k0 = 0; k0 < KTOT; k0 += 64) {
        __syncthreads();
        {   // stage + transpose: [64 k][128 m] -> As[m][k]
            int k = tid >> 2, mq = tid & 3;
            const uint32* src = A32 + ((size_t)(b * KTOT + k0 + k)) * 1024 + tloc + mq * 32;
            #pragma unroll
            for (int c = 0; c < 8; ++c) {
                uint4 v = *(const uint4*)(src + c * 4);
                As[mq * 32 + c * 4 + 0][k] = v.x;
                As[mq * 32 + c * 4 + 1][k] = v.y;
                As[mq * 32 + c * 4 + 2][k] = v.z;
                As[mq * 32 + c * 4 + 3][k] = v.w;
            }
        }
        __syncthreads();
        #pragma unroll
        for (int ks = 0; ks < 2; ++ks) {
            int kk = ks * 32 + lk8;
            bf16x8 aH[2], aL[2];
            #pragma unroll
            for (int mi = 0; mi < 2; ++mi) {
                int m = w * 32 + mi * 16 + lm;
                uint4 p0 = *(const uint4*)&As[m][kk];
                uint4 p1 = *(const uint4*)&As[m][kk + 4];
                uint32 u[8] = {p0.x, p0.y, p0.z, p0.w, p1.x, p1.y, p1.z, p1.w};
                bf16x8 h, lo;
                #pragma unroll
                for (int j = 0; j < 8; ++j) {
                    h[j]  = (short)(u[j] & 0xffffu);
                    lo[j] = (short)(u[j] >> 16);
                }
                aH[mi] = h; aL[mi] = lo;
            }
            #pragma unroll
            for (int ni = 0; ni < NF; ++ni) {
                int n = ni * 16 + lm;
                bf16x8 wH = {0,0,0,0,0,0,0,0}, wLo = {0,0,0,0,0,0,0,0};
                if (n < Nvalid) {
                    wH  = *(const bf16x8*)(Wh + (size_t)n * KTOT + k0 + ks * 32 + lk8);
                    wLo = *(const bf16x8*)(Wl + (size_t)n * KTOT + k0 + ks * 32 + lk8);
                }
                #pragma unroll
                for (int mi = 0; mi < 2; ++mi) {
                    acc[mi][ni] = __builtin_amdgcn_mfma_f32_16x16x32_bf16(aL[mi], wH,  acc[mi][ni], 0, 0, 0);
                    acc[mi][ni] = __builtin_amdgcn_mfma_f32_16x16x32_bf16(aH[mi], wLo, acc[mi][ni], 0, 0, 0);
                    acc[mi][ni] = __builtin_amdgcn_mfma_f32_16x16x32_bf16(aH[mi], wH,  acc[mi][ni], 0, 0, 0);
                }
            }
        }
    }
    int m0 = w * 32 + (l >> 4) * 4;
    #pragma unroll
    for (int ni = 0; ni < NF; ++ni) {
        int n = ni * 16 + lm;
        #pragma unroll
        for (int mi = 0; mi < 2; ++mi) {
            f32x4 v = acc[mi][ni];
            int mg = bm + m0 + mi * 16;
            if (Cnm) {
                if (n < Nvalid) *(f32x4*)(Cnm + (size_t)n * M_ + mg) = v;
            } else {
                #pragma unroll
                for (int r = 0; r < 4; ++r)
                    Cmn[(size_t)(mg + r) * Nvalid + n] = v[r];
            }
        }
    }
}

// ---------------------------------------------------------------- conv + silu -> packed uT32
__global__ __launch_bounds__(256) void conv_T_kernel(
        const float* __restrict__ xiT, const float* __restrict__ cw,
        const float* __restrict__ cb, uint32* __restrict__ uT32) {
    int wv = threadIdx.x >> 6, lane = threadIdx.x & 63;
    int rid = blockIdx.x * 4 + wv;            // b*256 + d
    int d = rid & 255;
    const float* src = xiT + (size_t)rid * 1024;
    int t0 = lane * 16;
    float x[20];
    {
        float4 p = (lane > 0) ? *(const float4*)(src + t0 - 4)
                              : make_float4(0.f, 0.f, 0.f, 0.f);
        *(float4*)&x[0] = p;
        #pragma unroll
        for (int c = 0; c < 4; ++c)
            *(float4*)&x[4 + c * 4] = *(const float4*)(src + t0 + c * 4);
    }
    float4 w4 = ((const float4*)cw)[d];
    float bias = cb[d];
    uint32* dst = uT32 + (size_t)rid * 1024 + t0;
    #pragma unroll
    for (int c = 0; c < 4; ++c) {
        uint4 o;
        uint32 ov[4];
        #pragma unroll
        for (int i = 0; i < 4; ++i) {
            int k = c * 4 + i;
            float acc = bias + x[k + 1] * w4.x + x[k + 2] * w4.y
                             + x[k + 3] * w4.z + x[k + 4] * w4.w;
            ov[i] = pack_pair(silu_f(acc));
        }
        o.x = ov[0]; o.y = ov[1]; o.z = ov[2]; o.w = ov[3];
        *(uint4*)(dst + c * 4) = o;
    }
}

// ---------------------------------------------------------------- dtT from dbcT (broadcast loads)
__global__ __launch_bounds__(256) void dtT_kernel(
        const float* __restrict__ dbcT, const float* __restrict__ dtW,
        const float* __restrict__ dtb, float* __restrict__ dtT) {
    int n = threadIdx.x;
    int m0 = blockIdx.x * 64;
    int b = m0 >> 10, t0 = m0 & 1023;
    float wk[8];
    *(float4*)&wk[0] = ((const float4*)dtW)[n * 2];
    *(float4*)&wk[4] = ((const float4*)dtW)[n * 2 + 1];
    float bias = dtb[n];
    float* dst = dtT + ((size_t)(b * 256 + n)) * 1024 + t0;
    for (int r4 = 0; r4 < 64; r4 += 4) {
        float col[8][4];
        #pragma unroll
        for (int k = 0; k < 8; ++k)
            *(float4*)col[k] = *(const float4*)(dbcT + (size_t)k * M_ + m0 + r4);
        float o[4];
        #pragma unroll
        for (int i = 0; i < 4; ++i) {
            float a = bias;
            #pragma unroll
            for (int k = 0; k < 8; ++k) a += col[k][i] * wk[k];
            o[i] = softplus_f(a);
        }
        *(float4*)(dst + r4) = make_float4(o[0], o[1], o[2], o[3]);
    }
}

// ---------------------------------------------------------------- scan v5 (packed u in, packed y out, B/C from dbcT)
__global__ __launch_bounds__(256) void scan5_kernel(
        const float* __restrict__ dtT, const uint32* __restrict__ uT32,
        const float* __restrict__ dbcT, const float* __restrict__ A_log,
        const float* __restrict__ zsilT, const float* __restrict__ Dp,
        uint32* __restrict__ yT32) {
    int wv = threadIdx.x >> 6, lane = threadIdx.x & 63;
    int wid = blockIdx.x * 4 + wv;            // b*256 + d
    int b = wid >> 8, d = wid & 255;
    size_t base = (size_t)wid * 1024 + lane * 16;

    float dt[16], du[16], y[16], pcA[16], pcB[16];
    {
        const float4* p = (const float4*)(dtT + base);
        const uint4*  q = (const uint4*)(uT32 + base);
        #pragma unroll
        for (int c = 0; c < 4; ++c) {
            float4 dv = p[c]; uint4 uv = q[c];
            dt[c * 4 + 0] = dv.x; dt[c * 4 + 1] = dv.y; dt[c * 4 + 2] = dv.z; dt[c * 4 + 3] = dv.w;
            du[c * 4 + 0] = dv.x * unpack_pair(uv.x);
            du[c * 4 + 1] = dv.y * unpack_pair(uv.y);
            du[c * 4 + 2] = dv.z * unpack_pair(uv.z);
            du[c * 4 + 3] = dv.w * unpack_pair(uv.w);
        }
        #pragma unroll
        for (int i = 0; i < 16; ++i) y[i] = 0.f;
    }
    const float* Bb = dbcT + (size_t)8  * M_ + (size_t)b * 1024 + lane * 16;
    const float* Cb = dbcT + (size_t)24 * M_ + (size_t)b * 1024 + lane * 16;
    const float* Arow = A_log + d * 16;

    for (int p = 0; p < 8; ++p) {
        int s0 = 2 * p, s1 = 2 * p + 1;
        float4 B0[4], B1[4], C0[4], C1[4];
        #pragma unroll
        for (int c = 0; c < 4; ++c) {
            B0[c] = *(const float4*)(Bb + (size_t)s0 * M_ + c * 4);
            B1[c] = *(const float4*)(Bb + (size_t)s1 * M_ + c * 4);
            C0[c] = *(const float4*)(Cb + (size_t)s0 * M_ + c * 4);
            C1[c] = *(const float4*)(Cb + (size_t)s1 * M_ + c * 4);
        }
        float A2a = -expf(Arow[s0]) * 1.4426950408889634f;
        float A2b = -expf(Arow[s1]) * 1.4426950408889634f;
        float h0 = 0.f, P0 = 1.f, h1 = 0.f, P1 = 1.f;
        #pragma unroll
        for (int c = 0; c < 4; ++c) {
            float Bv0[4] = {B0[c].x, B0[c].y, B0[c].z, B0[c].w};
            float Cv0[4] = {C0[c].x, C0[c].y, C0[c].z, C0[c].w};
            float Bv1[4] = {B1[c].x, B1[c].y, B1[c].z, B1[c].w};
            float Cv1[4] = {C1[c].x, C1[c].y, C1[c].z, C1[c].w};
            #pragma unroll
            for (int i = 0; i < 4; ++i) {
                int ii = c * 4 + i;
                float a0 = __builtin_amdgcn_exp2f(dt[ii] * A2a);
                float a1 = __builtin_amdgcn_exp2f(dt[ii] * A2b);
                h0 = a0 * h0 + du[ii] * Bv0[i];  P0 *= a0;
                h1 = a1 * h1 + du[ii] * Bv1[i];  P1 *= a1;
                y[ii] += h0 * Cv0[i] + h1 * Cv1[i];
                pcA[ii] = P0 * Cv0[i];
                pcB[ii] = P1 * Cv1[i];
            }
        }
        float Aag0 = P0, E0 = h0, Aag1 = P1, E1 = h1;
        #pragma unroll
        for (int dlt = 1; dlt < 64; dlt <<= 1) {
            float Au0 = __shfl_up(Aag0, dlt, 64), Eu0 = __shfl_up(E0, dlt, 64);
            float Au1 = __shfl_up(Aag1, dlt, 64), Eu1 = __shfl_up(E1, dlt, 64);
            if (lane >= dlt) {
                E0 = Aag0 * Eu0 + E0;  Aag0 *= Au0;
                E1 = Aag1 * Eu1 + E1;  Aag1 *= Au1;
            }
        }
        float car0 = __shfl_up(E0, 1, 64), car1 = __shfl_up(E1, 1, 64);
        if (lane == 0) { car0 = 0.f; car1 = 0.f; }
        #pragma unroll
        for (int i = 0; i < 16; ++i) y[i] += car0 * pcA[i] + car1 * pcB[i];
    }

    float Dv = Dp[d];
    const float4* qz = (const float4*)(zsilT + base);
    uint32* dst = yT32 + base;
    #pragma unroll
    for (int c = 0; c < 4; ++c) {
        float4 zv = qz[c];
        float za[4] = {zv.x, zv.y, zv.z, zv.w};
        uint32 ov[4];
        #pragma unroll
        for (int i = 0; i < 4; ++i) {
            int ii = c * 4 + i;
            float u = (dt[ii] > 0.f) ? du[ii] * __builtin_amdgcn_rcpf(dt[ii]) : 0.f;
            ov[i] = pack_pair((y[ii] + u * Dv) * za[i]);
        }
        uint4 o; o.x = ov[0]; o.y = ov[1]; o.z = ov[2]; o.w = ov[3];
        *(uint4*)(dst + c * 4) = o;
    }
}

// ---------------------------------------------------------------- final projection (C_OUT=7)
__global__ __launch_bounds__(256) void outproj_kernel(
        const float* __restrict__ x, const float* __restrict__ W,
        float* __restrict__ out) {
    int wv = threadIdx.x >> 6, lane = threadIdx.x & 63;
    size_t m = (size_t)blockIdx.x * 4 + wv;
    float x0 = x[m * 128 + lane], x1 = x[m * 128 + lane + 64];
    #pragma unroll
    for (int c = 0; c < 7; ++c) {
        float p = x0 * W[c * 128 + lane] + x1 * W[c * 128 + lane + 64];
        #pragma unroll
        for (int o = 1; o < 64; o <<= 1) p += __shfl_xor(p, o, 64);
        if (lane == 0) out[m * 7 + c] = p;
    }
}

// ================================================================ launch
extern "C" void kernel_launch(void* const* d_in, const int* in_sizes, int n_in,
                              void* d_out, int out_size, void* d_ws, size_t ws_size,
                              hipStream_t stream) {
    const float* x_enc  = (const float*)d_in[0];
    const float* x_mark = (const float*)d_in[1];
    const float* tokW   = (const float*)d_in[4];
    const float* tempW  = (const float*)d_in[5];
    const float* norm_w = (const float*)d_in[6];
    const float* norm_b = (const float*)d_in[7];
    const float* inW    = (const float*)d_in[8];
    const float* convW  = (const float*)d_in[9];
    const float* convB  = (const float*)d_in[10];
    const float* xpW    = (const float*)d_in[11];
    const float* dtW    = (const float*)d_in[12];
    const float* dtbp   = (const float*)d_in[13];
    const float* A_log  = (const float*)d_in[14];
    const float* Dp     = (const float*)d_in[15];
    const float* outW   = (const float*)d_in[16];
    const float* nfw    = (const float*)d_in[17];
    const float* nfb    = (const float*)d_in[18];
    const float* finW   = (const float*)d_in[19];
    float* out = (float*)d_out;

    float* ws = (float*)d_ws;
    size_t o = 0;
    float*  hidden   = ws + o; o += (size_t)M_ * DM;
    float*  residual = ws + o; o += (size_t)M_ * DM;
    float*  xlnF     = ws + o; o += (size_t)M_ * DM;   // final-LN fp32; layers alias bf16 planes:
    float*  xiT      = ws + o; o += (size_t)M_ * DI;
    float*  zsilT    = ws + o; o += (size_t)M_ * DI;
    uint32* uT32     = (uint32*)(ws + o); o += (size_t)M_ * DI;
    float*  dbcT     = ws + o; o += (size_t)M_ * 40;   // [40][M]; pe aliases front
    float*  dtT      = ws + o; o += (size_t)M_ * DI;
    uint32* yT32     = (uint32*)(ws + o); o += (size_t)M_ * DI;
    ush* inWh  = (ush*)(ws + o); o += (size_t)NL * 512 * DM / 2;
    ush* inWl  = (ush*)(ws + o); o += (size_t)NL * 512 * DM / 2;
    ush* xpWh  = (ush*)(ws + o); o += (size_t)NL * 40 * DI / 2;
    ush* xpWl  = (ush*)(ws + o); o += (size_t)NL * 40 * DI / 2;
    ush* outWh = (ush*)(ws + o); o += (size_t)NL * DM * DI / 2;
    ush* outWl = (ush*)(ws + o); o += (size_t)NL * DM * DI / 2;
    ush* xlnh = (ush*)xlnF;                    // bf16 planes alias final-LN buffer
    ush* xlnl = xlnh + (size_t)M_ * DM;
    float* pe = dbcT;                          // pe dead before dbcT written

    dim3 blk(256);
    pe_kernel<<<1024 * 64 / 256, blk, 0, stream>>>(pe);
    embed_kernel<<<M_ * DM / 256, blk, 0, stream>>>(x_enc, x_mark, tokW, tempW, pe, hidden);
    {
        int n1 = NL * 512 * DM, n2 = NL * 40 * DI, n3 = NL * DM * DI;
        cvt_pair_kernel<<<(n1 + 255) / 256, blk, 0, stream>>>(inW,  inWh,  inWl,  n1);
        cvt_pair_kernel<<<(n2 + 255) / 256, blk, 0, stream>>>(xpW,  xpWh,  xpWl,  n2);
        cvt_pair_kernel<<<(n3 + 255) / 256, blk, 0, stream>>>(outW, outWh, outWl, n3);
    }

    for (int l = 0; l < NL; ++l) {
        ln_kernel<<<M_ / 4, blk, 0, stream>>>(hidden, l ? residual : nullptr,
                                              norm_w + l * DM, norm_b + l * DM,
                                              nullptr, xlnh, xlnl, residual);
        gemm_inproj_mfma<<<dim3(4, M_ / 128), blk, 0, stream>>>(
            xlnh, xlnl, inWh + (size_t)l * 512 * DM, inWl + (size_t)l * 512 * DM,
            xiT, zsilT);
        conv_T_kernel<<<B_ * DI / 4, blk, 0, stream>>>(xiT, convW + l * DI * DC,
                                                       convB + l * DI, uT32);
        gemm_at_mfma<3, 256><<<M_ / 128, blk, 0, stream>>>(
            uT32, xpWh + (size_t)l * 40 * DI, xpWl + (size_t)l * 40 * DI,
            40, dbcT, nullptr);
        dtT_kernel<<<M_ / 64, blk, 0, stream>>>(dbcT, dtW + l * DI * DR,
                                                dtbp + l * DI, dtT);
        scan5_kernel<<<B_ * DI / 4, blk, 0, stream>>>(dtT, uT32, dbcT,
                                                      A_log + l * DI * DS, zsilT,
                                                      Dp + l * DI, yT32);
        gemm_at_mfma<8, 256><<<M_ / 128, blk, 0, stream>>>(
            yT32, outWh + (size_t)l * DM * DI, outWl + (size_t)l * DM * DI,
            128, nullptr, hidden);
    }

    ln_kernel<<<M_ / 4, blk, 0, stream>>>(hidden, residual, nfw, nfb,
                                          xlnF, nullptr, nullptr, nullptr);
    outproj_kernel<<<M_ / 4, blk, 0, stream>>>(xlnF, finW, out);
}

// Round 11
// 600.880 us; speedup vs baseline: 1.3297x; 1.0475x over previous
//
#include <hip/hip_runtime.h>
#include <math.h>

#define B_  32
#define L_  1024
#define M_  (B_*L_)      // 32768 rows
#define DM  128
#define DI  256
#define DS  16
#define DC  4
#define DR  8
#define NL  2

typedef unsigned int  uint32;
typedef unsigned short ush;
typedef __attribute__((ext_vector_type(8))) short bf16x8;
typedef __attribute__((ext_vector_type(4))) float f32x4;

__device__ __forceinline__ float silu_f(float x) { return x / (1.f + expf(-x)); }
__device__ __forceinline__ float softplus_f(float x) {
    return fmaxf(x, 0.f) + log1pf(expf(-fabsf(x)));
}
// bf16 RNE round
__device__ __forceinline__ ush f2bf(float x) {
    union { float f; uint32 u; } v; v.f = x;
    uint32 lsb = (v.u >> 16) & 1u;
    v.u += 0x7fffu + lsb;
    return (ush)(v.u >> 16);
}
__device__ __forceinline__ void split2(float x, ush& h, ush& l) {
    h = f2bf(x);
    float fh = __uint_as_float(((uint32)h) << 16);
    l = f2bf(x - fh);
}
__device__ __forceinline__ uint32 pack_pair(float x) {
    ush h, l; split2(x, h, l);
    return (uint32)h | ((uint32)l << 16);
}
__device__ __forceinline__ float unpack_pair(uint32 v) {
    return __uint_as_float(v << 16) + __uint_as_float(v & 0xffff0000u);
}

// ---------------------------------------------------------------- weight split
__global__ __launch_bounds__(256) void cvt_pair_kernel(
        const float* __restrict__ src, ush* __restrict__ h, ush* __restrict__ l, int n) {
    int i = blockIdx.x * 256 + threadIdx.x;
    if (i < n) { ush hh, ll; split2(src[i], hh, ll); h[i] = hh; l[i] = ll; }
}

// ---------------------------------------------------------------- PE table
__global__ __launch_bounds__(256) void pe_kernel(float* __restrict__ pe) {
    int idx = blockIdx.x * 256 + threadIdx.x;     // over 1024*64
    int t = idx >> 6, i = idx & 63;
    float div = expf(-0.07195578415606394f * (float)(2 * i));  // -ln(10000)/128
    float ang = (float)t * div;
    pe[t * 128 + 2 * i]     = sinf(ang);
    pe[t * 128 + 2 * i + 1] = cosf(ang);
}

// ---------------------------------------------------------------- embed
__global__ __launch_bounds__(256) void embed_kernel(
        const float* __restrict__ x_enc, const float* __restrict__ x_mark,
        const float* __restrict__ tokW, const float* __restrict__ tempW,
        const float* __restrict__ pe, float* __restrict__ out) {
    int idx = blockIdx.x * 256 + threadIdx.x;      // over M_*DM
    int d = idx & 127;
    int m = idx >> 7;
    int b = m >> 10, t = m & 1023;
    const float* xb = x_enc + (size_t)b * L_ * 7;
    float acc = pe[t * 128 + d];
    #pragma unroll
    for (int w = 0; w < 3; ++w) {
        int tt = t + w - 1;
        tt = (tt < 0) ? (L_ - 1) : (tt >= L_ ? 0 : tt);   // circular pad
        const float* xr = xb + tt * 7;
        #pragma unroll
        for (int f = 0; f < 7; ++f) acc += xr[f] * tokW[(d * 7 + f) * 3 + w];
    }
    const float* mr = x_mark + (size_t)m * 4;
    #pragma unroll
    for (int f = 0; f < 4; ++f) acc += mr[f] * tempW[d * 4 + f];
    out[idx] = acc;
}

// ---------------------------------------------------------------- layernorm (layer mode: bf16 hi/lo planes)
__global__ __launch_bounds__(256) void ln_kernel(
        const float* __restrict__ a, const float* __restrict__ b,
        const float* __restrict__ w, const float* __restrict__ bias,
        ush* __restrict__ outh, ush* __restrict__ outl,
        float* __restrict__ out_res) {
    int wv = threadIdx.x >> 6, lane = threadIdx.x & 63;
    size_t m = (size_t)blockIdx.x * 4 + wv;
    size_t base = m * DM;
    float x0 = a[base + lane], x1 = a[base + lane + 64];
    if (b) { x0 += b[base + lane]; x1 += b[base + lane + 64]; }
    out_res[base + lane] = x0; out_res[base + lane + 64] = x1;
    float s = x0 + x1;
    #pragma unroll
    for (int o = 1; o < 64; o <<= 1) s += __shfl_xor(s, o, 64);
    float mu = s * (1.f / 128.f);
    float d0 = x0 - mu, d1 = x1 - mu;
    float v = d0 * d0 + d1 * d1;
    #pragma unroll
    for (int o = 1; o < 64; o <<= 1) v += __shfl_xor(v, o, 64);
    float inv = rsqrtf(v * (1.f / 128.f) + 1e-5f);
    float r0 = d0 * inv * w[lane]      + bias[lane];
    float r1 = d1 * inv * w[lane + 64] + bias[lane + 64];
    ush h, l;
    split2(r0, h, l); outh[base + lane] = h;      outl[base + lane] = l;
    split2(r1, h, l); outh[base + lane + 64] = h; outl[base + lane + 64] = l;
}

// ---------------------------------------------------------------- final LN + out-projection (fused)
__global__ __launch_bounds__(256) void ln_out_kernel(
        const float* __restrict__ a, const float* __restrict__ b,
        const float* __restrict__ w, const float* __restrict__ bias,
        const float* __restrict__ finW, float* __restrict__ out) {
    int wv = threadIdx.x >> 6, lane = threadIdx.x & 63;
    size_t m = (size_t)blockIdx.x * 4 + wv;
    size_t base = m * DM;
    float x0 = a[base + lane] + b[base + lane];
    float x1 = a[base + lane + 64] + b[base + lane + 64];
    float s = x0 + x1;
    #pragma unroll
    for (int o = 1; o < 64; o <<= 1) s += __shfl_xor(s, o, 64);
    float mu = s * (1.f / 128.f);
    float d0 = x0 - mu, d1 = x1 - mu;
    float v = d0 * d0 + d1 * d1;
    #pragma unroll
    for (int o = 1; o < 64; o <<= 1) v += __shfl_xor(v, o, 64);
    float inv = rsqrtf(v * (1.f / 128.f) + 1e-5f);
    float r0 = d0 * inv * w[lane]      + bias[lane];
    float r1 = d1 * inv * w[lane + 64] + bias[lane + 64];
    #pragma unroll
    for (int c = 0; c < 7; ++c) {
        float p = r0 * finW[c * 128 + lane] + r1 * finW[c * 128 + lane + 64];
        #pragma unroll
        for (int o = 1; o < 64; o <<= 1) p += __shfl_xor(p, o, 64);
        if (lane == 0) out[m * 7 + c] = p;
    }
}

// ---------------------------------------------------------------- in_proj MFMA (split-bf16, no LDS)
__global__ __launch_bounds__(256) void gemm_inproj_mfma(
        const ush* __restrict__ Ah, const ush* __restrict__ Al,
        const ush* __restrict__ Wh, const ush* __restrict__ Wl,
        float* __restrict__ xiT, float* __restrict__ zsilT) {
    int bm = blockIdx.y * 128, bn = blockIdx.x * 128;
    int w = threadIdx.x >> 6, l = threadIdx.x & 63;
    int lm = l & 15, lk8 = (l >> 4) * 8;
    f32x4 acc[2][8];
    #pragma unroll
    for (int mi = 0; mi < 2; ++mi)
        #pragma unroll
        for (int ni = 0; ni < 8; ++ni) acc[mi][ni] = {0.f, 0.f, 0.f, 0.f};
    const ush* ah = Ah + (size_t)(bm + w * 32 + lm) * 128;
    const ush* al = Al + (size_t)(bm + w * 32 + lm) * 128;
    const ush* wh = Wh + (size_t)(bn + lm) * 128;
    const ush* wl = Wl + (size_t)(bn + lm) * 128;
    for (int k0 = 0; k0 < 128; k0 += 32) {
        bf16x8 aH[2], aL[2];
        #pragma unroll
        for (int mi = 0; mi < 2; ++mi) {
            aH[mi] = *(const bf16x8*)(ah + mi * 16 * 128 + k0 + lk8);
            aL[mi] = *(const bf16x8*)(al + mi * 16 * 128 + k0 + lk8);
        }
        #pragma unroll
        for (int ni = 0; ni < 8; ++ni) {
            bf16x8 wH = *(const bf16x8*)(wh + ni * 16 * 128 + k0 + lk8);
            bf16x8 wLo = *(const bf16x8*)(wl + ni * 16 * 128 + k0 + lk8);
            #pragma unroll
            for (int mi = 0; mi < 2; ++mi) {
                acc[mi][ni] = __builtin_amdgcn_mfma_f32_16x16x32_bf16(aL[mi], wH,  acc[mi][ni], 0, 0, 0);
                acc[mi][ni] = __builtin_amdgcn_mfma_f32_16x16x32_bf16(aH[mi], wLo, acc[mi][ni], 0, 0, 0);
                acc[mi][ni] = __builtin_amdgcn_mfma_f32_16x16x32_bf16(aH[mi], wH,  acc[mi][ni], 0, 0, 0);
            }
        }
    }
    int b = bm >> 10;
    int tl0 = (bm & 1023) + w * 32 + (l >> 4) * 4;
    #pragma unroll
    for (int ni = 0; ni < 8; ++ni) {
        int n = bn + ni * 16 + lm;
        #pragma unroll
        for (int mi = 0; mi < 2; ++mi) {
            int tl = tl0 + mi * 16;
            f32x4 v = acc[mi][ni];
            if (bn < 256) {
                *(f32x4*)(xiT + ((size_t)(b * 256 + n)) * 1024 + tl) = v;
            } else {
                f32x4 r;
                #pragma unroll
                for (int i = 0; i < 4; ++i) r[i] = silu_f(v[i]);
                *(f32x4*)(zsilT + ((size_t)(b * 256 + n - 256)) * 1024 + tl) = r;
            }
        }
    }
}

// ---------------------------------------------------------------- A-transposed MFMA GEMM (split-bf16)
template<int NF, int KTOT>
__global__ __launch_bounds__(256) void gemm_at_mfma(
        const uint32* __restrict__ A32, const ush* __restrict__ Wh,
        const ush* __restrict__ Wl, int Nvalid,
        float* __restrict__ Cnm, float* __restrict__ Cmn) {
    __shared__ uint32 As[128][68];   // BK=64 interleaved hi|lo
    int bm = blockIdx.x * 128;
    int b = bm >> 10, tloc = bm & 1023;
    int tid = threadIdx.x;
    int w = tid >> 6, l = tid & 63;
    int lm = l & 15, lk8 = (l >> 4) * 8;
    f32x4 acc[2][NF];
    #pragma unroll
    for (int mi = 0; mi < 2; ++mi)
        #pragma unroll
        for (int ni = 0; ni < NF; ++ni) acc[mi][ni] = {0.f, 0.f, 0.f, 0.f};

    for (int k0 = 0; k0 < KTOT; k0 += 64) {
        __syncthreads();
        {   // stage + transpose: [64 k][128 m] -> As[m][k]
            int k = tid >> 2, mq = tid & 3;
            const uint32* src = A32 + ((size_t)(b * KTOT + k0 + k)) * 1024 + tloc + mq * 32;
            #pragma unroll
            for (int c = 0; c < 8; ++c) {
                uint4 v = *(const uint4*)(src + c * 4);
                As[mq * 32 + c * 4 + 0][k] = v.x;
                As[mq * 32 + c * 4 + 1][k] = v.y;
                As[mq * 32 + c * 4 + 2][k] = v.z;
                As[mq * 32 + c * 4 + 3][k] = v.w;
            }
        }
        __syncthreads();
        #pragma unroll
        for (int ks = 0; ks < 2; ++ks) {
            int kk = ks * 32 + lk8;
            bf16x8 aH[2], aL[2];
            #pragma unroll
            for (int mi = 0; mi < 2; ++mi) {
                int m = w * 32 + mi * 16 + lm;
                uint4 p0 = *(const uint4*)&As[m][kk];
                uint4 p1 = *(const uint4*)&As[m][kk + 4];
                uint32 u[8] = {p0.x, p0.y, p0.z, p0.w, p1.x, p1.y, p1.z, p1.w};
                bf16x8 h, lo;
                #pragma unroll
                for (int j = 0; j < 8; ++j) {
                    h[j]  = (short)(u[j] & 0xffffu);
                    lo[j] = (short)(u[j] >> 16);
                }
                aH[mi] = h; aL[mi] = lo;
            }
            #pragma unroll
            for (int ni = 0; ni < NF; ++ni) {
                int n = ni * 16 + lm;
                bf16x8 wH = {0,0,0,0,0,0,0,0}, wLo = {0,0,0,0,0,0,0,0};
                if (n < Nvalid) {
                    wH  = *(const bf16x8*)(Wh + (size_t)n * KTOT + k0 + ks * 32 + lk8);
                    wLo = *(const bf16x8*)(Wl + (size_t)n * KTOT + k0 + ks * 32 + lk8);
                }
                #pragma unroll
                for (int mi = 0; mi < 2; ++mi) {
                    acc[mi][ni] = __builtin_amdgcn_mfma_f32_16x16x32_bf16(aL[mi], wH,  acc[mi][ni], 0, 0, 0);
                    acc[mi][ni] = __builtin_amdgcn_mfma_f32_16x16x32_bf16(aH[mi], wLo, acc[mi][ni], 0, 0, 0);
                    acc[mi][ni] = __builtin_amdgcn_mfma_f32_16x16x32_bf16(aH[mi], wH,  acc[mi][ni], 0, 0, 0);
                }
            }
        }
    }
    int m0 = w * 32 + (l >> 4) * 4;
    #pragma unroll
    for (int ni = 0; ni < NF; ++ni) {
        int n = ni * 16 + lm;
        #pragma unroll
        for (int mi = 0; mi < 2; ++mi) {
            f32x4 v = acc[mi][ni];
            int mg = bm + m0 + mi * 16;
            if (Cnm) {
                if (n < Nvalid) *(f32x4*)(Cnm + (size_t)n * M_ + mg) = v;
            } else {
                #pragma unroll
                for (int r = 0; r < 4; ++r)
                    Cmn[(size_t)(mg + r) * Nvalid + n] = v[r];
            }
        }
    }
}

// ---------------------------------------------------------------- conv + silu -> packed uT32
__global__ __launch_bounds__(256) void conv_T_kernel(
        const float* __restrict__ xiT, const float* __restrict__ cw,
        const float* __restrict__ cb, uint32* __restrict__ uT32) {
    int wv = threadIdx.x >> 6, lane = threadIdx.x & 63;
    int rid = blockIdx.x * 4 + wv;            // b*256 + d
    int d = rid & 255;
    const float* src = xiT + (size_t)rid * 1024;
    int t0 = lane * 16;
    float x[20];
    {
        float4 p = (lane > 0) ? *(const float4*)(src + t0 - 4)
                              : make_float4(0.f, 0.f, 0.f, 0.f);
        *(float4*)&x[0] = p;
        #pragma unroll
        for (int c = 0; c < 4; ++c)
            *(float4*)&x[4 + c * 4] = *(const float4*)(src + t0 + c * 4);
    }
    float4 w4 = ((const float4*)cw)[d];
    float bias = cb[d];
    uint32* dst = uT32 + (size_t)rid * 1024 + t0;
    #pragma unroll
    for (int c = 0; c < 4; ++c) {
        uint4 o;
        uint32 ov[4];
        #pragma unroll
        for (int i = 0; i < 4; ++i) {
            int k = c * 4 + i;
            float acc = bias + x[k + 1] * w4.x + x[k + 2] * w4.y
                             + x[k + 3] * w4.z + x[k + 4] * w4.w;
            ov[i] = pack_pair(silu_f(acc));
        }
        o.x = ov[0]; o.y = ov[1]; o.z = ov[2]; o.w = ov[3];
        *(uint4*)(dst + c * 4) = o;
    }
}

// ---------------------------------------------------------------- scan v6: fused dt-proj + softplus, 2-state KS
__global__ __launch_bounds__(256) void scan6_kernel(
        const uint32* __restrict__ uT32, const float* __restrict__ dbcT,
        const float* __restrict__ A_log, const float* __restrict__ zsilT,
        const float* __restrict__ Dp, const float* __restrict__ dtW,
        const float* __restrict__ dtb, uint32* __restrict__ yT32) {
    int wv = threadIdx.x >> 6, lane = threadIdx.x & 63;
    int wid = blockIdx.x * 4 + wv;            // b*256 + d
    int b = wid >> 8, d = wid & 255;
    size_t base = (size_t)wid * 1024 + lane * 16;
    size_t m0 = (size_t)b * 1024 + lane * 16;  // dbcT column base

    float wk[8];
    *(float4*)&wk[0] = ((const float4*)dtW)[d * 2];
    *(float4*)&wk[4] = ((const float4*)dtW)[d * 2 + 1];
    float bias = dtb[d];

    float dt[16], du[16], y[16], pcA[16], pcB[16];
    // dt = softplus(dbcT[0..8] . wk + bias), du = dt * u
    {
        const uint4* q = (const uint4*)(uT32 + base);
        #pragma unroll
        for (int c = 0; c < 4; ++c) {
            float col[8][4];
            #pragma unroll
            for (int k = 0; k < 8; ++k)
                *(float4*)col[k] = *(const float4*)(dbcT + (size_t)k * M_ + m0 + c * 4);
            uint4 uv = q[c];
            uint32 ua[4] = {uv.x, uv.y, uv.z, uv.w};
            #pragma unroll
            for (int i = 0; i < 4; ++i) {
                float a = bias;
                #pragma unroll
                for (int k = 0; k < 8; ++k) a = fmaf(col[k][i], wk[k], a);
                float dtv = softplus_f(a);
                dt[c * 4 + i] = dtv;
                du[c * 4 + i] = dtv * unpack_pair(ua[i]);
            }
        }
        #pragma unroll
        for (int i = 0; i < 16; ++i) y[i] = 0.f;
    }
    const float* Bb = dbcT + (size_t)8  * M_ + m0;
    const float* Cb = dbcT + (size_t)24 * M_ + m0;
    const float* Arow = A_log + d * 16;

    for (int p = 0; p < 8; ++p) {
        int s0 = 2 * p, s1 = 2 * p + 1;
        float4 B0[4], B1[4], C0[4], C1[4];
        #pragma unroll
        for (int c = 0; c < 4; ++c) {
            B0[c] = *(const float4*)(Bb + (size_t)s0 * M_ + c * 4);
            B1[c] = *(const float4*)(Bb + (size_t)s1 * M_ + c * 4);
            C0[c] = *(const float4*)(Cb + (size_t)s0 * M_ + c * 4);
            C1[c] = *(const float4*)(Cb + (size_t)s1 * M_ + c * 4);
        }
        float A2a = -expf(Arow[s0]) * 1.4426950408889634f;
        float A2b = -expf(Arow[s1]) * 1.4426950408889634f;
        float h0 = 0.f, P0 = 1.f, h1 = 0.f, P1 = 1.f;
        #pragma unroll
        for (int c = 0; c < 4; ++c) {
            float Bv0[4] = {B0[c].x, B0[c].y, B0[c].z, B0[c].w};
            float Cv0[4] = {C0[c].x, C0[c].y, C0[c].z, C0[c].w};
            float Bv1[4] = {B1[c].x, B1[c].y, B1[c].z, B1[c].w};
            float Cv1[4] = {C1[c].x, C1[c].y, C1[c].z, C1[c].w};
            #pragma unroll
            for (int i = 0; i < 4; ++i) {
                int ii = c * 4 + i;
                float a0 = __builtin_amdgcn_exp2f(dt[ii] * A2a);
                float a1 = __builtin_amdgcn_exp2f(dt[ii] * A2b);
                h0 = a0 * h0 + du[ii] * Bv0[i];  P0 *= a0;
                h1 = a1 * h1 + du[ii] * Bv1[i];  P1 *= a1;
                y[ii] += h0 * Cv0[i] + h1 * Cv1[i];
                pcA[ii] = P0 * Cv0[i];
                pcB[ii] = P1 * Cv1[i];
            }
        }
        float Aag0 = P0, E0 = h0, Aag1 = P1, E1 = h1;
        #pragma unroll
        for (int dlt = 1; dlt < 64; dlt <<= 1) {
            float Au0 = __shfl_up(Aag0, dlt, 64), Eu0 = __shfl_up(E0, dlt, 64);
            float Au1 = __shfl_up(Aag1, dlt, 64), Eu1 = __shfl_up(E1, dlt, 64);
            if (lane >= dlt) {
                E0 = Aag0 * Eu0 + E0;  Aag0 *= Au0;
                E1 = Aag1 * Eu1 + E1;  Aag1 *= Au1;
            }
        }
        float car0 = __shfl_up(E0, 1, 64), car1 = __shfl_up(E1, 1, 64);
        if (lane == 0) { car0 = 0.f; car1 = 0.f; }
        #pragma unroll
        for (int i = 0; i < 16; ++i) y[i] += car0 * pcA[i] + car1 * pcB[i];
    }

    float Dv = Dp[d];
    const float4* qz = (const float4*)(zsilT + base);
    uint32* dst = yT32 + base;
    #pragma unroll
    for (int c = 0; c < 4; ++c) {
        float4 zv = qz[c];
        float za[4] = {zv.x, zv.y, zv.z, zv.w};
        uint32 ov[4];
        #pragma unroll
        for (int i = 0; i < 4; ++i) {
            int ii = c * 4 + i;
            float u = (dt[ii] > 0.f) ? du[ii] * __builtin_amdgcn_rcpf(dt[ii]) : 0.f;
            ov[i] = pack_pair((y[ii] + u * Dv) * za[i]);
        }
        uint4 o; o.x = ov[0]; o.y = ov[1]; o.z = ov[2]; o.w = ov[3];
        *(uint4*)(dst + c * 4) = o;
    }
}

// ================================================================ launch
extern "C" void kernel_launch(void* const* d_in, const int* in_sizes, int n_in,
                              void* d_out, int out_size, void* d_ws, size_t ws_size,
                              hipStream_t stream) {
    const float* x_enc  = (const float*)d_in[0];
    const float* x_mark = (const float*)d_in[1];
    const float* tokW   = (const float*)d_in[4];
    const float* tempW  = (const float*)d_in[5];
    const float* norm_w = (const float*)d_in[6];
    const float* norm_b = (const float*)d_in[7];
    const float* inW    = (const float*)d_in[8];
    const float* convW  = (const float*)d_in[9];
    const float* convB  = (const float*)d_in[10];
    const float* xpW    = (const float*)d_in[11];
    const float* dtW    = (const float*)d_in[12];
    const float* dtbp   = (const float*)d_in[13];
    const float* A_log  = (const float*)d_in[14];
    const float* Dp     = (const float*)d_in[15];
    const float* outW   = (const float*)d_in[16];
    const float* nfw    = (const float*)d_in[17];
    const float* nfb    = (const float*)d_in[18];
    const float* finW   = (const float*)d_in[19];
    float* out = (float*)d_out;

    float* ws = (float*)d_ws;
    size_t o = 0;
    float*  hidden   = ws + o; o += (size_t)M_ * DM;
    float*  residual = ws + o; o += (size_t)M_ * DM;
    float*  xlnP     = ws + o; o += (size_t)M_ * DM;   // hosts bf16 hi/lo planes
    float*  xiT      = ws + o; o += (size_t)M_ * DI;
    float*  zsilT    = ws + o; o += (size_t)M_ * DI;
    uint32* uT32     = (uint32*)(ws + o); o += (size_t)M_ * DI;
    float*  dbcT     = ws + o; o += (size_t)M_ * 40;   // [40][M]; pe aliases front
    uint32* yT32     = (uint32*)(ws + o); o += (size_t)M_ * DI;
    ush* inWh  = (ush*)(ws + o); o += (size_t)NL * 512 * DM / 2;
    ush* inWl  = (ush*)(ws + o); o += (size_t)NL * 512 * DM / 2;
    ush* xpWh  = (ush*)(ws + o); o += (size_t)NL * 40 * DI / 2;
    ush* xpWl  = (ush*)(ws + o); o += (size_t)NL * 40 * DI / 2;
    ush* outWh = (ush*)(ws + o); o += (size_t)NL * DM * DI / 2;
    ush* outWl = (ush*)(ws + o); o += (size_t)NL * DM * DI / 2;
    ush* xlnh = (ush*)xlnP;
    ush* xlnl = xlnh + (size_t)M_ * DM;
    float* pe = dbcT;                          // pe dead before dbcT written

    dim3 blk(256);
    pe_kernel<<<1024 * 64 / 256, blk, 0, stream>>>(pe);
    embed_kernel<<<M_ * DM / 256, blk, 0, stream>>>(x_enc, x_mark, tokW, tempW, pe, hidden);
    {
        int n1 = NL * 512 * DM, n2 = NL * 40 * DI, n3 = NL * DM * DI;
        cvt_pair_kernel<<<(n1 + 255) / 256, blk, 0, stream>>>(inW,  inWh,  inWl,  n1);
        cvt_pair_kernel<<<(n2 + 255) / 256, blk, 0, stream>>>(xpW,  xpWh,  xpWl,  n2);
        cvt_pair_kernel<<<(n3 + 255) / 256, blk, 0, stream>>>(outW, outWh, outWl, n3);
    }

    for (int l = 0; l < NL; ++l) {
        ln_kernel<<<M_ / 4, blk, 0, stream>>>(hidden, l ? residual : nullptr,
                                              norm_w + l * DM, norm_b + l * DM,
                                              xlnh, xlnl, residual);
        gemm_inproj_mfma<<<dim3(4, M_ / 128), blk, 0, stream>>>(
            xlnh, xlnl, inWh + (size_t)l * 512 * DM, inWl + (size_t)l * 512 * DM,
            xiT, zsilT);
        conv_T_kernel<<<B_ * DI / 4, blk, 0, stream>>>(xiT, convW + l * DI * DC,
                                                       convB + l * DI, uT32);
        gemm_at_mfma<3, 256><<<M_ / 128, blk, 0, stream>>>(
            uT32, xpWh + (size_t)l * 40 * DI, xpWl + (size_t)l * 40 * DI,
            40, dbcT, nullptr);
        scan6_kernel<<<B_ * DI / 4, blk, 0, stream>>>(uT32, dbcT,
                                                      A_log + l * DI * DS, zsilT,
                                                      Dp + l * DI,
                                                      dtW + (size_t)l * DI * DR,
                                                      dtbp + l * DI, yT32);
        gemm_at_mfma<8, 256><<<M_ / 128, blk, 0, stream>>>(
            yT32, outWh + (size_t)l * DM * DI, outWl + (size_t)l * DM * DI,
            128, nullptr, hidden);
    }

    ln_out_kernel<<<M_ / 4, blk, 0, stream>>>(hidden, residual, nfw, nfb, finW, out);
}